// Round 1
// baseline (5206.416 us; speedup 1.0000x reference)
//
#include <hip/hip_runtime.h>
#include <math.h>

// StarTransformer forward, fp32 baseline.
// B=4, L=1024, H=1024, NH=16, HD=64, ND=1024, ITERS=4, ring window U=5 (+2 extra keys).

namespace {

constexpr int B_ = 4, L_ = 1024, H_ = 1024, NH_ = 16, HD_ = 64, ND_ = 1024, ITERS_ = 4;

// ---------- transpose data [B,L,H] -> embs/nodes [B,H,L] ----------
__global__ void k_transpose_in(const float* __restrict__ data,
                               float* __restrict__ embs,
                               float* __restrict__ nodes) {
  __shared__ float t[32][33];
  int b = blockIdx.z;
  int h0 = blockIdx.x * 32, l0 = blockIdx.y * 32;
  int tx = threadIdx.x, ty = threadIdx.y;
#pragma unroll
  for (int j = 0; j < 4; ++j)
    t[ty + j * 8][tx] = data[((size_t)b * L_ + l0 + ty + j * 8) * H_ + h0 + tx];
  __syncthreads();
#pragma unroll
  for (int j = 0; j < 4; ++j) {
    float vv = t[tx][ty + j * 8];
    size_t o = ((size_t)b * H_ + h0 + ty + j * 8) * L_ + l0 + tx;
    embs[o] = vv;
    nodes[o] = vv;
  }
}

// ---------- relay[b,c] = mean_l data[b,l,c] ----------
__global__ void k_relay_init(const float* __restrict__ data, float* __restrict__ relay) {
  int b = blockIdx.y;
  int c = blockIdx.x * 256 + threadIdx.x;
  const float* p = data + (size_t)b * L_ * H_ + c;
  float acc = 0.f;
  for (int l = 0; l < L_; ++l) acc += p[(size_t)l * H_];
  relay[b * H_ + c] = acc * (1.f / (float)L_);
}

// ---------- LayerNorm over channel dim of [B,H,L] ----------
__global__ void k_layernorm(const float* __restrict__ x, const float* __restrict__ s,
                            const float* __restrict__ bb, float* __restrict__ y) {
  int b = blockIdx.y;
  int ls = threadIdx.x & 63;
  int cg = threadIdx.x >> 6;  // 4 channel groups
  int l = blockIdx.x * 64 + ls;
  const float* base = x + (size_t)b * H_ * L_ + l;
  float sum = 0.f, sq = 0.f;
  for (int c = cg; c < H_; c += 4) {
    float v = base[(size_t)c * L_];
    sum += v;
    sq += v * v;
  }
  __shared__ float ssum[4][64], ssq[4][64];
  ssum[cg][ls] = sum;
  ssq[cg][ls] = sq;
  __syncthreads();
  float tot = ssum[0][ls] + ssum[1][ls] + ssum[2][ls] + ssum[3][ls];
  float tsq = ssq[0][ls] + ssq[1][ls] + ssq[2][ls] + ssq[3][ls];
  float mu = tot * (1.f / (float)H_);
  float var = tsq * (1.f / (float)H_) - mu * mu;
  float rstd = rsqrtf(var + 1e-5f);
  float* yb = y + (size_t)b * H_ * L_ + l;
  for (int c = cg; c < H_; c += 4) {
    float v = base[(size_t)c * L_];
    yb[(size_t)c * L_] = (v - mu) * rstd * s[c] + bb[c];
  }
}

// ---------- GEMM: Y[b,o,l] = sum_c W[o,c]*X[b,c,l] + bias[o] ----------
// X is [B, C, L_] (ld = L_). Y row stride = ldo, column offset ooff.
// MODE 0: plain write.  MODE 1: Y[idx] += leaky_relu(val)  (Y = nodes).
template <int MODE>
__global__ __launch_bounds__(256) void k_gemm(const float* __restrict__ W,
                                              const float* __restrict__ bias,
                                              const float* __restrict__ X,
                                              float* __restrict__ Y,
                                              int O, int C, int ldo, int ooff) {
  constexpr int BM = 64, BN = 64, BK = 16;
  __shared__ float sW[BK][BM + 4];
  __shared__ float sX[BK][BN + 4];
  int b = blockIdx.z;
  int bo = blockIdx.y * BM;
  int bn = blockIdx.x * BN;
  int tid = threadIdx.x;
  const float* Xb = X + (size_t)b * C * L_;
  int ty = tid >> 4, tx = tid & 15;
  int wm = tid >> 2, wk0 = (tid & 3) * 4;
  int xk = tid >> 4, xn0 = (tid & 15) * 4;
  float acc[4][4] = {};
  for (int ck = 0; ck < C; ck += BK) {
    float4 wv = *reinterpret_cast<const float4*>(W + (size_t)(bo + wm) * C + ck + wk0);
    float4 xv = *reinterpret_cast<const float4*>(Xb + (size_t)(ck + xk) * L_ + bn + xn0);
    sW[wk0 + 0][wm] = wv.x;
    sW[wk0 + 1][wm] = wv.y;
    sW[wk0 + 2][wm] = wv.z;
    sW[wk0 + 3][wm] = wv.w;
    *reinterpret_cast<float4*>(&sX[xk][xn0]) = xv;  // row stride 68 floats -> 16B aligned
    __syncthreads();
#pragma unroll
    for (int kk = 0; kk < BK; ++kk) {
      float a[4], bv[4];
#pragma unroll
      for (int i = 0; i < 4; ++i) a[i] = sW[kk][ty * 4 + i];
#pragma unroll
      for (int j = 0; j < 4; ++j) bv[j] = sX[kk][tx * 4 + j];
#pragma unroll
      for (int i = 0; i < 4; ++i)
#pragma unroll
        for (int j = 0; j < 4; ++j) acc[i][j] = fmaf(a[i], bv[j], acc[i][j]);
    }
    __syncthreads();
  }
#pragma unroll
  for (int i = 0; i < 4; ++i) {
    float bs = bias[bo + ty * 4 + i];
    size_t row = ((size_t)b * O + bo + ty * 4 + i) * (size_t)ldo + ooff + bn + tx * 4;
#pragma unroll
    for (int j = 0; j < 4; ++j) {
      float val = acc[i][j] + bs;
      if (MODE == 0) {
        Y[row + j] = val;
      } else {
        float r = val > 0.f ? val : 0.01f * val;
        Y[row + j] += r;
      }
    }
  }
}

// ---------- matvec: y[b, o] = dot(W[o,:], x[b,:]) + bias[o]; C fixed 1024 ----------
__global__ void k_matvec(const float* __restrict__ W, const float* __restrict__ bias,
                         const float* __restrict__ x, float* __restrict__ y,
                         long strideB, long strideO, int leaky) {
  int b = blockIdx.y;
  int o = blockIdx.x * 256 + threadIdx.x;
  __shared__ float sx[1024];
  for (int c = threadIdx.x; c < 1024; c += 256) sx[c] = x[(size_t)b * 1024 + c];
  __syncthreads();
  const float* wr = W + (size_t)o * 1024;
  float acc = 0.f;
  for (int c = 0; c < 1024; c += 4) {
    float4 wv = *reinterpret_cast<const float4*>(wr + c);
    acc += wv.x * sx[c] + wv.y * sx[c + 1] + wv.z * sx[c + 2] + wv.w * sx[c + 3];
  }
  acc += bias[o];
  if (leaky) acc = acc > 0.f ? acc : 0.01f * acc;
  y[(size_t)b * strideB + (size_t)o * strideO] = acc;
}

// ---------- msa1 ring attention: one thread per (b,n,l) ----------
// keys: u=0..4 ring window (zero-padded OOB -> score contribution 0, NOT masked),
// u=5 embs-key, u=6 relay-key. softmax over the 7.
__global__ void k_msa1(const float* __restrict__ q, const float* __restrict__ k,
                       const float* __restrict__ v, const float* __restrict__ ke,
                       const float* __restrict__ ve, const float* __restrict__ rk,
                       const float* __restrict__ rv, float* __restrict__ att) {
  int l = blockIdx.x * 256 + threadIdx.x;
  int n = blockIdx.y, b = blockIdx.z;
  size_t base = ((size_t)(b * NH_ + n) * HD_) * L_ + l;
  size_t rb = (size_t)(b * NH_ + n) * HD_;
  bool va[5];
#pragma unroll
  for (int u = 0; u < 5; ++u) {
    int lk = l + u - 2;
    va[u] = (lk >= 0) && (lk < L_);
  }
  float s[7] = {0.f, 0.f, 0.f, 0.f, 0.f, 0.f, 0.f};
  for (int d = 0; d < HD_; ++d) {
    size_t off = base + (size_t)d * L_;
    float qd = q[off];
    const float* kd = k + off;
#pragma unroll
    for (int u = 0; u < 5; ++u)
      if (va[u]) s[u] = fmaf(qd, kd[u - 2], s[u]);
    s[5] = fmaf(qd, ke[off], s[5]);
    s[6] = fmaf(qd, rk[rb + d], s[6]);
  }
  float m = -1e30f;
#pragma unroll
  for (int u = 0; u < 7; ++u) {
    s[u] *= 0.125f;  // 1/sqrt(64)
    m = fmaxf(m, s[u]);
  }
  float e[7], tot = 0.f;
#pragma unroll
  for (int u = 0; u < 7; ++u) {
    e[u] = expf(s[u] - m);
    tot += e[u];
  }
  float inv = 1.f / tot;
#pragma unroll
  for (int u = 0; u < 7; ++u) e[u] *= inv;
  for (int d = 0; d < HD_; ++d) {
    size_t off = base + (size_t)d * L_;
    const float* vd = v + off;
    float a = e[5] * ve[off] + e[6] * rv[rb + d];
#pragma unroll
    for (int u = 0; u < 5; ++u)
      if (va[u]) a = fmaf(e[u], vd[u - 2], a);
    att[off] = a;
  }
}

// ---------- msa2 star attention: one block per (b,n); v = k (faithful) ----------
__global__ __launch_bounds__(256) void k_msa2(const float* __restrict__ rq,
                                              const float* __restrict__ kk,
                                              const int* __restrict__ mask,
                                              float* __restrict__ satt) {
  int n = blockIdx.x, b = blockIdx.y;
  int tid = threadIdx.x;
  __shared__ float sq_[HD_];
  __shared__ float mred[4], sred[4];
  __shared__ float wsum[4][HD_];
  size_t rb = (size_t)(b * NH_ + n) * HD_;
  if (tid < HD_) sq_[tid] = rq[rb + tid];
  __syncthreads();
  const float* kb = kk + rb * (size_t)(L_ + 1);
  float pre[5];
  float lmax = -1e30f;
#pragma unroll
  for (int j = 0; j < 5; ++j) {
    int p = tid + j * 256;
    float val = -1e30f;
    if (p < L_ + 1) {
      if (p > 0 && mask[b * L_ + p - 1] == 0) {
        val = -1e10f;
      } else {
        float acc = 0.f;
        for (int d = 0; d < HD_; ++d) acc = fmaf(sq_[d], kb[(size_t)d * (L_ + 1) + p], acc);
        val = acc * 0.125f;
      }
    }
    pre[j] = val;
    lmax = fmaxf(lmax, val);
  }
  int lane = tid & 63, wave = tid >> 6;
#pragma unroll
  for (int off = 32; off > 0; off >>= 1) lmax = fmaxf(lmax, __shfl_down(lmax, off));
  if (lane == 0) mred[wave] = lmax;
  __syncthreads();
  float gmax = fmaxf(fmaxf(mred[0], mred[1]), fmaxf(mred[2], mred[3]));
  float e[5];
  float lsum = 0.f;
#pragma unroll
  for (int j = 0; j < 5; ++j) {
    int p = tid + j * 256;
    e[j] = (p < L_ + 1) ? expf(pre[j] - gmax) : 0.f;  // masked -> exp(-1e10-..) == 0
    lsum += e[j];
  }
  float ls2 = lsum;
#pragma unroll
  for (int off = 32; off > 0; off >>= 1) ls2 += __shfl_down(ls2, off);
  if (lane == 0) sred[wave] = ls2;
  __syncthreads();
  float inv = 1.f / (sred[0] + sred[1] + sred[2] + sred[3]);
  float acc[HD_];
#pragma unroll
  for (int d = 0; d < HD_; ++d) acc[d] = 0.f;
#pragma unroll
  for (int j = 0; j < 5; ++j) {
    int p = tid + j * 256;
    if (p < L_ + 1) {
      float ej = e[j];
#pragma unroll
      for (int d = 0; d < HD_; ++d) acc[d] = fmaf(ej, kb[(size_t)d * (L_ + 1) + p], acc[d]);
    }
  }
#pragma unroll
  for (int d = 0; d < HD_; ++d) {
    float xv = acc[d];
#pragma unroll
    for (int off = 32; off > 0; off >>= 1) xv += __shfl_down(xv, off);
    if (lane == 0) wsum[wave][d] = xv;
  }
  __syncthreads();
  if (tid < HD_) {
    float t = wsum[0][tid] + wsum[1][tid] + wsum[2][tid] + wsum[3][tid];
    satt[rb + tid] = t * inv;
  }
}

// ---------- zero nodes at padding positions ----------
__global__ void k_maskzero(float* __restrict__ nodes, const int* __restrict__ mask) {
  size_t idx = (size_t)blockIdx.x * 256 + threadIdx.x;  // over B*H*L = 2^22
  int l = (int)(idx & (L_ - 1));
  int b = (int)(idx >> 20);  // H_*L_ = 2^20
  if (mask[b * L_ + l] == 0) nodes[idx] = 0.f;
}

// ---------- nodes [B,H,L] -> out [B,L,H] ----------
__global__ void k_final(const float* __restrict__ nodes, float* __restrict__ out) {
  __shared__ float t[32][33];
  int b = blockIdx.z;
  int l0 = blockIdx.x * 32, h0 = blockIdx.y * 32;
  int tx = threadIdx.x, ty = threadIdx.y;
#pragma unroll
  for (int j = 0; j < 4; ++j)
    t[ty + j * 8][tx] = nodes[((size_t)b * H_ + h0 + ty + j * 8) * L_ + l0 + tx];
  __syncthreads();
#pragma unroll
  for (int j = 0; j < 4; ++j)
    out[((size_t)b * L_ + l0 + ty + j * 8) * H_ + h0 + tx] = t[tx][ty + j * 8];
}

__global__ void k_copy_relay(const float* __restrict__ relay, float* __restrict__ out) {
  int i = blockIdx.x * 256 + threadIdx.x;
  out[i] = relay[i];
}

}  // namespace

extern "C" void kernel_launch(void* const* d_in, const int* in_sizes, int n_in,
                              void* d_out, int out_size, void* d_ws, size_t ws_size,
                              hipStream_t stream) {
  (void)in_sizes; (void)n_in; (void)out_size; (void)ws_size;
  const float* data = (const float*)d_in[0];
  const int* mask = (const int*)d_in[1];
  const float* ln_s = (const float*)d_in[2];
  const float* ln_b = (const float*)d_in[3];
  const float* rwq = (const float*)d_in[4];
  const float* rwq_b = (const float*)d_in[5];
  const float* rwk = (const float*)d_in[6];
  const float* rwk_b = (const float*)d_in[7];
  const float* rwv = (const float*)d_in[8];
  const float* rwv_b = (const float*)d_in[9];
  const float* rwo = (const float*)d_in[10];
  const float* rwo_b = (const float*)d_in[11];
  const float* swq = (const float*)d_in[12];
  const float* swq_b = (const float*)d_in[13];
  const float* swk = (const float*)d_in[14];
  const float* swk_b = (const float*)d_in[15];
  const float* swo = (const float*)d_in[16];
  const float* swo_b = (const float*)d_in[17];
  float* out = (float*)d_out;

  const size_t SZ = (size_t)B_ * ND_ * L_;  // 4M floats = 16 MiB
  float* ws = (float*)d_ws;
  float* embs = ws;
  float* nodes = embs + SZ;
  float* xn = nodes + SZ;  // reused as att
  float* q = xn + SZ;
  float* kbuf = q + SZ;
  float* vbuf = kbuf + SZ;
  float* ke = vbuf + SZ;
  float* ve = ke + SZ;
  float* kkb = ve + SZ;  // [B, ND, L+1]
  float* relay = kkb + (size_t)B_ * ND_ * (L_ + 1);
  float* rk = relay + B_ * H_;
  float* rv = rk + B_ * ND_;
  float* rq = rv + B_ * ND_;
  float* satt = rq + B_ * ND_;

  dim3 tpb(32, 8);
  k_transpose_in<<<dim3(H_ / 32, L_ / 32, B_), tpb, 0, stream>>>(data, embs, nodes);
  k_relay_init<<<dim3(H_ / 256, B_), 256, 0, stream>>>(data, relay);

  dim3 gg(L_ / 64, 1024 / 64, B_);
  dim3 gmv(4, B_);
  for (int i = 0; i < ITERS_; ++i) {
    const float* wq_i = rwq + (size_t)i * ND_ * H_;
    const float* wk_i = rwk + (size_t)i * ND_ * H_;
    const float* wv_i = rwv + (size_t)i * ND_ * H_;
    const float* wo_i = rwo + (size_t)i * H_ * ND_;
    const float* sq_i = swq + (size_t)i * ND_ * H_;
    const float* sk_i = swk + (size_t)i * ND_ * H_;
    const float* so_i = swo + (size_t)i * H_ * ND_;

    k_layernorm<<<dim3(L_ / 64, B_), 256, 0, stream>>>(nodes, ln_s + i * H_, ln_b + i * H_, xn);
    k_gemm<0><<<gg, 256, 0, stream>>>(wq_i, rwq_b + i * ND_, xn, q, ND_, H_, L_, 0);
    k_gemm<0><<<gg, 256, 0, stream>>>(wk_i, rwk_b + i * ND_, xn, kbuf, ND_, H_, L_, 0);
    k_gemm<0><<<gg, 256, 0, stream>>>(wv_i, rwv_b + i * ND_, xn, vbuf, ND_, H_, L_, 0);
    k_gemm<0><<<gg, 256, 0, stream>>>(wk_i, rwk_b + i * ND_, embs, ke, ND_, H_, L_, 0);
    k_gemm<0><<<gg, 256, 0, stream>>>(wv_i, rwv_b + i * ND_, embs, ve, ND_, H_, L_, 0);
    k_matvec<<<gmv, 256, 0, stream>>>(wk_i, rwk_b + i * ND_, relay, rk, ND_, 1, 0);
    k_matvec<<<gmv, 256, 0, stream>>>(wv_i, rwv_b + i * ND_, relay, rv, ND_, 1, 0);
    k_msa1<<<dim3(L_ / 256, NH_, B_), 256, 0, stream>>>(q, kbuf, vbuf, ke, ve, rk, rv, xn);
    // nodes += leaky(Wo @ att + bo)
    k_gemm<1><<<gg, 256, 0, stream>>>(wo_i, rwo_b + i * H_, xn, nodes, H_, ND_, L_, 0);
    // star attention inputs (uses OLD relay, and nodes BEFORE zeroing)
    k_matvec<<<gmv, 256, 0, stream>>>(sq_i, swq_b + i * ND_, relay, rq, ND_, 1, 0);
    k_matvec<<<gmv, 256, 0, stream>>>(sk_i, swk_b + i * ND_, relay, kkb,
                                      (long)ND_ * (L_ + 1), L_ + 1, 0);
    k_gemm<0><<<gg, 256, 0, stream>>>(sk_i, swk_b + i * ND_, nodes, kkb, ND_, H_, L_ + 1, 1);
    k_msa2<<<dim3(NH_, B_), 256, 0, stream>>>(rq, kkb, mask, satt);
    k_matvec<<<gmv, 256, 0, stream>>>(so_i, swo_b + i * H_, satt, relay, H_, 1, 1);
    k_maskzero<<<(B_ * H_ * L_) / 256, 256, 0, stream>>>(nodes, mask);
  }
  k_final<<<dim3(L_ / 32, H_ / 32, B_), tpb, 0, stream>>>(nodes, out);
  k_copy_relay<<<dim3((B_ * H_) / 256), 256, 0, stream>>>(relay, out + (size_t)B_ * L_ * H_);
}

// Round 2
// 1543.635 us; speedup vs baseline: 3.3728x; 3.3728x over previous
//
#include <hip/hip_runtime.h>
#include <math.h>

namespace {

constexpr int B_ = 4, L_ = 1024, H_ = 1024, NH_ = 16, HD_ = 64, ND_ = 1024, ITERS_ = 4;

typedef unsigned short u16;
typedef __attribute__((ext_vector_type(8))) short short8;
typedef __attribute__((ext_vector_type(4))) float f32x4;

__device__ inline u16 f2bf(float f) {
  unsigned u = __builtin_bit_cast(unsigned, f);
  u += 0x7FFFu + ((u >> 16) & 1u);
  return (u16)(u >> 16);
}

__device__ inline void gl_lds16(const u16* g, u16* l) {
  __builtin_amdgcn_global_load_lds((const __attribute__((address_space(1))) void*)g,
                                   (__attribute__((address_space(3))) void*)l, 16, 0, 0);
}

// ---------- fp32 -> bf16 conversion (count multiple of 4) ----------
__global__ void k_f2bf(const float* __restrict__ src, u16* __restrict__ dst, int n4) {
  int i = blockIdx.x * 256 + threadIdx.x;
  if (i < n4) {
    float4 v = reinterpret_cast<const float4*>(src)[i];
    ushort4 o;
    o.x = f2bf(v.x); o.y = f2bf(v.y); o.z = f2bf(v.z); o.w = f2bf(v.w);
    reinterpret_cast<ushort4*>(dst)[i] = o;
  }
}

// ---------- data [B,L,H] -> nodes [B,H,L] ----------
__global__ void k_transpose_in(const float* __restrict__ data, float* __restrict__ nodes) {
  __shared__ float t[32][33];
  int b = blockIdx.z;
  int h0 = blockIdx.x * 32, l0 = blockIdx.y * 32;
  int tx = threadIdx.x, ty = threadIdx.y;
#pragma unroll
  for (int j = 0; j < 4; ++j)
    t[ty + j * 8][tx] = data[((size_t)b * L_ + l0 + ty + j * 8) * H_ + h0 + tx];
  __syncthreads();
#pragma unroll
  for (int j = 0; j < 4; ++j)
    nodes[((size_t)b * H_ + h0 + ty + j * 8) * L_ + l0 + tx] = t[tx][ty + j * 8];
}

// ---------- relay init (two-phase, deterministic) ----------
__global__ void k_relay_part(const float* __restrict__ data, float* __restrict__ part) {
  int b = blockIdx.z, chunk = blockIdx.y;
  int c = blockIdx.x * 256 + threadIdx.x;
  const float* p = data + ((size_t)b * L_ + chunk * 128) * H_ + c;
  float acc = 0.f;
  for (int l = 0; l < 128; ++l) acc += p[(size_t)l * H_];
  part[((size_t)b * 8 + chunk) * H_ + c] = acc;
}
__global__ void k_relay_reduce(const float* __restrict__ part, float* __restrict__ relay) {
  int i = blockIdx.x * 256 + threadIdx.x;  // B*H
  int b = i >> 10, c = i & 1023;
  float acc = 0.f;
  for (int j = 0; j < 8; ++j) acc += part[((size_t)b * 8 + j) * H_ + c];
  relay[i] = acc * (1.f / (float)L_);
}

// ---------- LayerNorm over channels; output bf16 transposed [B][L][H] ----------
__global__ __launch_bounds__(256) void k_layernorm_bf(const float* __restrict__ x,
                                                      const float* __restrict__ s,
                                                      const float* __restrict__ bb,
                                                      u16* __restrict__ y) {
  int b = blockIdx.y, l0 = blockIdx.x * 64;
  int t = threadIdx.x;
  int ls = t & 63, cg = t >> 6;
  const float* base = x + (size_t)b * H_ * L_ + l0 + ls;
  float sum = 0.f, sq = 0.f;
  for (int c = cg; c < H_; c += 4) {
    float v = base[(size_t)c * L_];
    sum += v; sq += v * v;
  }
  __shared__ float ssum[4][64], ssq[4][64];
  __shared__ float smu[64], srs[64];
  ssum[cg][ls] = sum; ssq[cg][ls] = sq;
  __syncthreads();
  if (cg == 0) {
    float tot = ssum[0][ls] + ssum[1][ls] + ssum[2][ls] + ssum[3][ls];
    float tsq = ssq[0][ls] + ssq[1][ls] + ssq[2][ls] + ssq[3][ls];
    float mu = tot * (1.f / (float)H_);
    float var = tsq * (1.f / (float)H_) - mu * mu;
    smu[ls] = mu;
    srs[ls] = rsqrtf(var + 1e-5f);
  }
  __syncthreads();
  __shared__ u16 T[64][68];
  int lw = t >> 2, cs = (t & 3) * 16;
  u16* dstbase = y + ((size_t)b * L_ + l0 + lw) * H_;
  for (int cc = 0; cc < H_; cc += 64) {
#pragma unroll
    for (int sub = 0; sub < 16; ++sub) {
      int cl = cg + sub * 4;
      int c = cc + cl;
      float v = base[(size_t)c * L_];
      T[cl][ls] = f2bf((v - smu[ls]) * srs[ls] * s[c] + bb[c]);
    }
    __syncthreads();
    u16 tmp[16];
#pragma unroll
    for (int j = 0; j < 16; ++j) tmp[j] = T[cs + j][lw];
    reinterpret_cast<uint4*>(dstbase + cc + cs)[0] = reinterpret_cast<uint4*>(tmp)[0];
    reinterpret_cast<uint4*>(dstbase + cc + cs)[1] = reinterpret_cast<uint4*>(tmp)[1];
    __syncthreads();
  }
}

// ---------- bf16 MFMA GEMM ----------
// Computes Y[b][o][l] = sum_c W[o][c] * Xact[c][l] (+bias[o]) where the
// activation is stored TRANSPOSED: X[b][l][c] bf16. MFMA operands:
// A = X-frag (M-dim = l), B = W-frag (N-dim = o). D: col=lane&15 -> o,
// row=(lane>>4)*4+reg -> l (4 consecutive l per lane => float4 stores).
// Tile: BM=128 (l) x BN=64 (o) x BK=32. 4 waves, each 64l x 32o.
// MODE 0: Y = val. MODE 1: Y += leaky(val); Ybf[l][o] = bf16(Y). MODE 2: scalar
// stores with ldo/ooff (kkb).
template <int MODE>
__global__ __launch_bounds__(256) void k_gemm_bf(const u16* __restrict__ W,
                                                 const float* __restrict__ bias,
                                                 const u16* __restrict__ X,
                                                 float* __restrict__ Y,
                                                 u16* __restrict__ Ybf,
                                                 int ldo, int ooff) {
  __shared__ __align__(16) u16 sA[128 * 32];  // [l_local][32]  (swizzled k-slots)
  __shared__ __align__(16) u16 sB[64 * 32];   // [o_local][32]
  const int b = blockIdx.z;
  const int bm = blockIdx.x * 128;  // l
  const int bn = blockIdx.y * 64;   // o
  const int t = threadIdx.x;
  const int w = t >> 6, lane = t & 63;
  const int wm = w >> 1, wn = w & 1;
  const int r4 = lane >> 2, slot = lane & 3;

  const u16* Xb = X + ((size_t)b * 1024 + bm) * 1024;

  const int rowA0 = w * 16 + r4;
  const int rowA1 = 64 + rowA0;
  const int colA0 = ((slot ^ ((rowA0 >> 1) & 3)) << 3);
  const int colA1 = ((slot ^ ((rowA1 >> 1) & 3)) << 3);
  const int rowB = w * 16 + r4;
  const int colB = ((slot ^ ((rowB >> 1) & 3)) << 3);
  const u16* gA0 = Xb + (size_t)rowA0 * 1024 + colA0;
  const u16* gA1 = Xb + (size_t)rowA1 * 1024 + colA1;
  const u16* gB = W + (size_t)(bn + rowB) * 1024 + colB;
  u16* lA0 = sA + (size_t)w * 512;
  u16* lA1 = sA + (size_t)(4 + w) * 512;
  u16* lB = sB + (size_t)w * 512;

  // fragment LDS indices (swizzle slot same for all mf/nf since offsets are mult of 16)
  const int kb_ = lane >> 4;
  const int kidx = ((kb_ ^ ((lane >> 1) & 3)) << 3);
  const int rA = wm * 64 + (lane & 15);
  const int rB2 = wn * 32 + (lane & 15);

  f32x4 acc[4][2];
#pragma unroll
  for (int mf = 0; mf < 4; ++mf)
#pragma unroll
    for (int nf = 0; nf < 2; ++nf) acc[mf][nf] = f32x4{0.f, 0.f, 0.f, 0.f};

  for (int ck = 0; ck < 1024; ck += 32) {
    gl_lds16(gA0, lA0);
    gl_lds16(gA1, lA1);
    gl_lds16(gB, lB);
    gA0 += 32; gA1 += 32; gB += 32;
    __syncthreads();
    short8 af[4], bfr[2];
#pragma unroll
    for (int mf = 0; mf < 4; ++mf)
      af[mf] = *reinterpret_cast<const short8*>(&sA[(rA + mf * 16) * 32 + kidx]);
#pragma unroll
    for (int nf = 0; nf < 2; ++nf)
      bfr[nf] = *reinterpret_cast<const short8*>(&sB[(rB2 + nf * 16) * 32 + kidx]);
#pragma unroll
    for (int mf = 0; mf < 4; ++mf)
#pragma unroll
      for (int nf = 0; nf < 2; ++nf)
        acc[mf][nf] = __builtin_amdgcn_mfma_f32_16x16x32_bf16(af[mf], bfr[nf], acc[mf][nf], 0, 0, 0);
    __syncthreads();
  }

#pragma unroll
  for (int nf = 0; nf < 2; ++nf) {
    int o = bn + wn * 32 + nf * 16 + (lane & 15);
    float bs = bias[o];
#pragma unroll
    for (int mf = 0; mf < 4; ++mf) {
      int l = bm + wm * 64 + mf * 16 + ((lane >> 4) << 2);
      f32x4 v = acc[mf][nf];
      if (MODE == 0) {
        size_t yi = ((size_t)(b * 1024 + o)) * (size_t)ldo + ooff + l;
        f32x4 ov = {v[0] + bs, v[1] + bs, v[2] + bs, v[3] + bs};
        *reinterpret_cast<f32x4*>(&Y[yi]) = ov;
      } else if (MODE == 1) {
        size_t yi = ((size_t)(b * 1024 + o)) * 1024 + l;
        f32x4 cur = *reinterpret_cast<const f32x4*>(&Y[yi]);
        f32x4 nv;
#pragma unroll
        for (int r = 0; r < 4; ++r) {
          float val = v[r] + bs;
          val = val > 0.f ? val : 0.01f * val;
          nv[r] = cur[r] + val;
        }
        *reinterpret_cast<f32x4*>(&Y[yi]) = nv;
#pragma unroll
        for (int r = 0; r < 4; ++r)
          Ybf[((size_t)(b * 1024 + l + r)) * 1024 + o] = f2bf(nv[r]);
      } else {
        size_t yi = ((size_t)(b * 1024 + o)) * (size_t)ldo + ooff + l;
#pragma unroll
        for (int r = 0; r < 4; ++r) Y[yi + r] = v[r] + bs;
      }
    }
  }
}

// ---------- matvec: wave per output ----------
__global__ __launch_bounds__(256) void k_matvec(const float* __restrict__ W,
                                                const float* __restrict__ bias,
                                                const float* __restrict__ x,
                                                float* __restrict__ y,
                                                long strideB, long strideO, int leaky) {
  int b = blockIdx.y;
  int o = blockIdx.x * 4 + (threadIdx.x >> 6);
  int lane = threadIdx.x & 63;
  const float* wr = W + (size_t)o * 1024;
  const float* xb = x + (size_t)b * 1024;
  float acc = 0.f;
  for (int c = lane; c < 1024; c += 64) acc += wr[c] * xb[c];
#pragma unroll
  for (int off = 32; off; off >>= 1) acc += __shfl_xor(acc, off);
  if (lane == 0) {
    acc += bias[o];
    if (leaky) acc = acc > 0.f ? acc : 0.01f * acc;
    y[(size_t)b * strideB + (size_t)o * strideO] = acc;
  }
}

// ---------- msa1 ring attention: 4 lanes per l, 16 d each ----------
__global__ __launch_bounds__(256) void k_msa1(const float* __restrict__ q,
                                              const float* __restrict__ k,
                                              const float* __restrict__ v,
                                              const float* __restrict__ ke,
                                              const float* __restrict__ ve,
                                              const float* __restrict__ rk,
                                              const float* __restrict__ rv,
                                              u16* __restrict__ attbf) {
  int t = threadIdx.x;
  int l = blockIdx.x * 64 + (t >> 2);
  int dg = t & 3;
  int n = blockIdx.y, b = blockIdx.z;
  size_t rb = (size_t)((b * NH_ + n) * HD_) + dg * 16;
  size_t base = rb * (size_t)L_ + l;
  bool inner = (l >= 2) && (l <= L_ - 3);
  float s[7] = {0.f, 0.f, 0.f, 0.f, 0.f, 0.f, 0.f};
  for (int i = 0; i < 16; ++i) {
    size_t off = base + (size_t)i * L_;
    float qd = q[off];
    const float* kd = k + off;
    s[5] = fmaf(qd, ke[off], s[5]);
    s[6] = fmaf(qd, rk[rb + i], s[6]);
    if (inner) {
      s[0] = fmaf(qd, kd[-2], s[0]);
      s[1] = fmaf(qd, kd[-1], s[1]);
      s[2] = fmaf(qd, kd[0], s[2]);
      s[3] = fmaf(qd, kd[1], s[3]);
      s[4] = fmaf(qd, kd[2], s[4]);
    } else {
#pragma unroll
      for (int u = 0; u < 5; ++u) {
        int lk = l + u - 2;
        if (lk >= 0 && lk < L_) s[u] = fmaf(qd, kd[u - 2], s[u]);
      }
    }
  }
#pragma unroll
  for (int u = 0; u < 7; ++u) {
    s[u] += __shfl_xor(s[u], 1);
    s[u] += __shfl_xor(s[u], 2);
  }
  float m = -1e30f;
#pragma unroll
  for (int u = 0; u < 7; ++u) {
    s[u] *= 0.125f;
    m = fmaxf(m, s[u]);
  }
  float e[7], tot = 0.f;
#pragma unroll
  for (int u = 0; u < 7; ++u) {
    e[u] = expf(s[u] - m);
    tot += e[u];
  }
  float inv = 1.f / tot;
#pragma unroll
  for (int u = 0; u < 7; ++u) e[u] *= inv;
  u16 outv[16];
  for (int i = 0; i < 16; ++i) {
    size_t off = base + (size_t)i * L_;
    const float* vd = v + off;
    float a = e[5] * ve[off] + e[6] * rv[rb + i];
    if (inner) {
      a = fmaf(e[0], vd[-2], a);
      a = fmaf(e[1], vd[-1], a);
      a = fmaf(e[2], vd[0], a);
      a = fmaf(e[3], vd[1], a);
      a = fmaf(e[4], vd[2], a);
    } else {
#pragma unroll
      for (int u = 0; u < 5; ++u) {
        int lk = l + u - 2;
        if (lk >= 0 && lk < L_) a = fmaf(e[u], vd[u - 2], a);
      }
    }
    outv[i] = f2bf(a);
  }
  u16* dst = attbf + ((size_t)b * L_ + l) * 1024 + n * 64 + dg * 16;
  reinterpret_cast<uint4*>(dst)[0] = reinterpret_cast<uint4*>(outv)[0];
  reinterpret_cast<uint4*>(dst)[1] = reinterpret_cast<uint4*>(outv)[1];
}

// ---------- msa2 star attention: 1024 threads per (b,n); v = k (faithful) ----------
__global__ __launch_bounds__(1024) void k_msa2(const float* __restrict__ rq,
                                               const float* __restrict__ kk,
                                               const int* __restrict__ mask,
                                               float* __restrict__ satt) {
  int n = blockIdx.x, b = blockIdx.y;
  int t = threadIdx.x;
  __shared__ float sq_[HD_];
  __shared__ float se[L_ + 1];
  __shared__ float swsum[16];
  __shared__ float stot;
  size_t rb = (size_t)(b * NH_ + n) * HD_;
  if (t < HD_) sq_[t] = rq[rb + t];
  __syncthreads();
  const float* kb = kk + rb * (size_t)(L_ + 1);
  float ls = 0.f;
  for (int p = t; p < L_ + 1; p += 1024) {
    float e;
    if (p > 0 && mask[b * L_ + p - 1] == 0) {
      e = 0.f;  // exp(-1e10 - max) == 0
    } else {
      float acc = 0.f;
      for (int d = 0; d < HD_; ++d) acc = fmaf(sq_[d], kb[(size_t)d * (L_ + 1) + p], acc);
      e = expf(acc * 0.125f);
    }
    se[p] = e;
    ls += e;
  }
  int lane = t & 63, w = t >> 6;
#pragma unroll
  for (int off = 32; off; off >>= 1) ls += __shfl_xor(ls, off);
  if (lane == 0) swsum[w] = ls;
  __syncthreads();
  if (t == 0) {
    float tot = 0.f;
    for (int j = 0; j < 16; ++j) tot += swsum[j];
    stot = 1.f / tot;
  }
  __syncthreads();
  float inv = stot;
  float acc[4] = {0.f, 0.f, 0.f, 0.f};
  const float* kw = kb + (size_t)(w * 4) * (L_ + 1);
  for (int p = lane; p < L_ + 1; p += 64) {
    float e = se[p];
#pragma unroll
    for (int j = 0; j < 4; ++j) acc[j] = fmaf(e, kw[(size_t)j * (L_ + 1) + p], acc[j]);
  }
#pragma unroll
  for (int j = 0; j < 4; ++j) {
    float a = acc[j];
#pragma unroll
    for (int off = 32; off; off >>= 1) a += __shfl_xor(a, off);
    if (lane == 0) satt[rb + w * 4 + j] = a * inv;
  }
}

// ---------- zero nodes at padding positions ----------
__global__ void k_maskzero(float* __restrict__ nodes, const int* __restrict__ mask) {
  size_t idx = (size_t)blockIdx.x * 256 + threadIdx.x;
  int l = (int)(idx & (L_ - 1));
  int b = (int)(idx >> 20);
  if (mask[b * L_ + l] == 0) nodes[idx] = 0.f;
}

// ---------- nodes [B,H,L] -> out [B,L,H] ----------
__global__ void k_final(const float* __restrict__ nodes, float* __restrict__ out) {
  __shared__ float t[32][33];
  int b = blockIdx.z;
  int l0 = blockIdx.x * 32, h0 = blockIdx.y * 32;
  int tx = threadIdx.x, ty = threadIdx.y;
#pragma unroll
  for (int j = 0; j < 4; ++j)
    t[ty + j * 8][tx] = nodes[((size_t)b * H_ + h0 + ty + j * 8) * L_ + l0 + tx];
  __syncthreads();
#pragma unroll
  for (int j = 0; j < 4; ++j)
    out[((size_t)b * L_ + l0 + ty + j * 8) * H_ + h0 + tx] = t[tx][ty + j * 8];
}

__global__ void k_copy_relay(const float* __restrict__ relay, float* __restrict__ out) {
  int i = blockIdx.x * 256 + threadIdx.x;
  out[i] = relay[i];
}

}  // namespace

extern "C" void kernel_launch(void* const* d_in, const int* in_sizes, int n_in,
                              void* d_out, int out_size, void* d_ws, size_t ws_size,
                              hipStream_t stream) {
  (void)in_sizes; (void)n_in; (void)out_size; (void)ws_size;
  const float* data = (const float*)d_in[0];
  const int* mask = (const int*)d_in[1];
  const float* ln_s = (const float*)d_in[2];
  const float* ln_b = (const float*)d_in[3];
  const float* rwq = (const float*)d_in[4];
  const float* rwq_b = (const float*)d_in[5];
  const float* rwk = (const float*)d_in[6];
  const float* rwk_b = (const float*)d_in[7];
  const float* rwv = (const float*)d_in[8];
  const float* rwv_b = (const float*)d_in[9];
  const float* rwo = (const float*)d_in[10];
  const float* rwo_b = (const float*)d_in[11];
  const float* swq = (const float*)d_in[12];
  const float* swq_b = (const float*)d_in[13];
  const float* swk = (const float*)d_in[14];
  const float* swk_b = (const float*)d_in[15];
  const float* swo = (const float*)d_in[16];
  const float* swo_b = (const float*)d_in[17];
  float* out = (float*)d_out;

  const size_t SZ = (size_t)B_ * ND_ * L_;  // 4M
  float* f = (float*)d_ws;
  float* nodes = f; f += SZ;
  float* q = f; f += SZ;
  float* kbuf = f; f += SZ;
  float* vbuf = f; f += SZ;
  float* ke = f; f += SZ;
  float* ve = f; f += SZ;
  float* kkb = f; f += (size_t)B_ * ND_ * (L_ + 1);
  float* part = f; f += (size_t)B_ * 8 * H_;
  float* relay = f; f += B_ * H_;
  float* rk = f; f += B_ * ND_;
  float* rv = f; f += B_ * ND_;
  float* rq = f; f += B_ * ND_;
  float* satt = f; f += B_ * ND_;
  u16* u = (u16*)f;
  u16* xn_bf = u; u += SZ;
  u16* embs_bf = u; u += SZ;
  u16* att_bf = u; u += SZ;
  u16* nodes_bf = u; u += SZ;
  u16* wq_bf = u; u += SZ;    // [4][1024][1024]
  u16* wk_bf = u; u += SZ;
  u16* wv_bf = u; u += SZ;
  u16* wo_bf = u; u += SZ;
  u16* swk_bf = u; u += SZ;

  // conversions (weights all iters + data)
  k_f2bf<<<4096, 256, 0, stream>>>(data, embs_bf, (int)(SZ / 4));
  k_f2bf<<<4096, 256, 0, stream>>>(rwq, wq_bf, (int)(SZ / 4));
  k_f2bf<<<4096, 256, 0, stream>>>(rwk, wk_bf, (int)(SZ / 4));
  k_f2bf<<<4096, 256, 0, stream>>>(rwv, wv_bf, (int)(SZ / 4));
  k_f2bf<<<4096, 256, 0, stream>>>(rwo, wo_bf, (int)(SZ / 4));
  k_f2bf<<<4096, 256, 0, stream>>>(swk, swk_bf, (int)(SZ / 4));

  dim3 tpb(32, 8);
  k_transpose_in<<<dim3(H_ / 32, L_ / 32, B_), tpb, 0, stream>>>(data, nodes);
  k_relay_part<<<dim3(H_ / 256, 8, B_), 256, 0, stream>>>(data, part);
  k_relay_reduce<<<dim3((B_ * H_) / 256), 256, 0, stream>>>(part, relay);

  dim3 gg(8, 16, B_);   // l-tiles(128), o-tiles(64), batch
  dim3 gmv(256, B_);    // wave per output
  for (int i = 0; i < ITERS_; ++i) {
    const u16* wq_i = wq_bf + (size_t)i * ND_ * H_;
    const u16* wk_i = wk_bf + (size_t)i * ND_ * H_;
    const u16* wv_i = wv_bf + (size_t)i * ND_ * H_;
    const u16* wo_i = wo_bf + (size_t)i * H_ * ND_;
    const u16* sk_i = swk_bf + (size_t)i * ND_ * H_;

    k_layernorm_bf<<<dim3(L_ / 64, B_), 256, 0, stream>>>(nodes, ln_s + i * H_, ln_b + i * H_, xn_bf);
    k_gemm_bf<0><<<gg, 256, 0, stream>>>(wq_i, rwq_b + i * ND_, xn_bf, q, nullptr, L_, 0);
    k_gemm_bf<0><<<gg, 256, 0, stream>>>(wk_i, rwk_b + i * ND_, xn_bf, kbuf, nullptr, L_, 0);
    k_gemm_bf<0><<<gg, 256, 0, stream>>>(wv_i, rwv_b + i * ND_, xn_bf, vbuf, nullptr, L_, 0);
    k_gemm_bf<0><<<gg, 256, 0, stream>>>(wk_i, rwk_b + i * ND_, embs_bf, ke, nullptr, L_, 0);
    k_gemm_bf<0><<<gg, 256, 0, stream>>>(wv_i, rwv_b + i * ND_, embs_bf, ve, nullptr, L_, 0);
    k_matvec<<<gmv, 256, 0, stream>>>(rwk + (size_t)i * ND_ * H_, rwk_b + i * ND_, relay, rk, ND_, 1, 0);
    k_matvec<<<gmv, 256, 0, stream>>>(rwv + (size_t)i * ND_ * H_, rwv_b + i * ND_, relay, rv, ND_, 1, 0);
    k_msa1<<<dim3(L_ / 64, NH_, B_), 256, 0, stream>>>(q, kbuf, vbuf, ke, ve, rk, rv, att_bf);
    // nodes += leaky(Wo @ att + bo); nodes_bf = bf16(nodes)
    k_gemm_bf<1><<<gg, 256, 0, stream>>>(wo_i, rwo_b + i * H_, att_bf, nodes, nodes_bf, L_, 0);
    // star attention (old relay; nodes before zeroing)
    k_matvec<<<gmv, 256, 0, stream>>>(swq + (size_t)i * ND_ * H_, swq_b + i * ND_, relay, rq, ND_, 1, 0);
    k_matvec<<<gmv, 256, 0, stream>>>(swk + (size_t)i * ND_ * H_, swk_b + i * ND_, relay, kkb,
                                      (long)ND_ * (L_ + 1), L_ + 1, 0);
    k_gemm_bf<2><<<gg, 256, 0, stream>>>(sk_i, swk_b + i * ND_, nodes_bf, kkb, nullptr, L_ + 1, 1);
    k_msa2<<<dim3(NH_, B_), 1024, 0, stream>>>(rq, kkb, mask, satt);
    k_matvec<<<gmv, 256, 0, stream>>>(swo + (size_t)i * H_ * ND_, swo_b + i * H_, satt, relay, H_, 1, 1);
    k_maskzero<<<(B_ * H_ * L_) / 256, 256, 0, stream>>>(nodes, mask);
  }
  k_final<<<dim3(L_ / 32, H_ / 32, B_), tpb, 0, stream>>>(nodes, out);
  k_copy_relay<<<dim3((B_ * H_) / 256), 256, 0, stream>>>(relay, out + (size_t)B_ * L_ * H_);
}

// Round 3
// 1181.210 us; speedup vs baseline: 4.4077x; 1.3068x over previous
//
#include <hip/hip_runtime.h>
#include <math.h>

namespace {

constexpr int B_ = 4, L_ = 1024, H_ = 1024, NH_ = 16, HD_ = 64, ND_ = 1024, ITERS_ = 4;

typedef unsigned short u16;
typedef __attribute__((ext_vector_type(8))) short short8;
typedef __attribute__((ext_vector_type(4))) float f32x4;

__device__ inline u16 f2bf(float f) {
  unsigned u = __builtin_bit_cast(unsigned, f);
  u += 0x7FFFu + ((u >> 16) & 1u);
  return (u16)(u >> 16);
}

__device__ inline void gl_lds16(const u16* g, u16* l) {
  __builtin_amdgcn_global_load_lds((const __attribute__((address_space(1))) void*)g,
                                   (__attribute__((address_space(3))) void*)l, 16, 0, 0);
}

// ---------- fp32 -> bf16 conversion ----------
__global__ void k_f2bf(const float* __restrict__ src, u16* __restrict__ dst, int n4) {
  int i = blockIdx.x * 256 + threadIdx.x;
  if (i < n4) {
    float4 v = reinterpret_cast<const float4*>(src)[i];
    ushort4 o;
    o.x = f2bf(v.x); o.y = f2bf(v.y); o.z = f2bf(v.z); o.w = f2bf(v.w);
    reinterpret_cast<ushort4*>(dst)[i] = o;
  }
}

// ---------- float4 copy ----------
__global__ void k_copy4(const float* __restrict__ src, float* __restrict__ dst) {
  int i = blockIdx.x * 256 + threadIdx.x;
  reinterpret_cast<float4*>(dst)[i] = reinterpret_cast<const float4*>(src)[i];
}

// ---------- relay init (two-phase, deterministic) ----------
__global__ void k_relay_part(const float* __restrict__ data, float* __restrict__ part) {
  int b = blockIdx.z, chunk = blockIdx.y;
  int c = blockIdx.x * 256 + threadIdx.x;
  const float* p = data + ((size_t)b * L_ + chunk * 128) * H_ + c;
  float acc = 0.f;
  for (int l = 0; l < 128; ++l) acc += p[(size_t)l * H_];
  part[((size_t)b * 8 + chunk) * H_ + c] = acc;
}
__global__ void k_relay_reduce(const float* __restrict__ part, float* __restrict__ relay) {
  int i = blockIdx.x * 256 + threadIdx.x;  // B*H
  int b = i >> 10, c = i & 1023;
  float acc = 0.f;
  for (int j = 0; j < 8; ++j) acc += part[((size_t)b * 8 + j) * H_ + c];
  relay[i] = acc * (1.f / (float)L_);
}

// ---------- LayerNorm over channels; x [B,L,H] fp32 -> y [B,L,H] bf16 ----------
// One wave per row; float4 coalesced; no LDS.
__global__ __launch_bounds__(256) void k_layernorm_bf(const float* __restrict__ x,
                                                      const float* __restrict__ s,
                                                      const float* __restrict__ bb,
                                                      u16* __restrict__ y) {
  int row = blockIdx.x * 4 + (threadIdx.x >> 6);  // over B*L
  int lane = threadIdx.x & 63;
  const float4* xr = reinterpret_cast<const float4*>(x + (size_t)row * H_);
  float4 v[4];
  float sum = 0.f, sq = 0.f;
#pragma unroll
  for (int j = 0; j < 4; ++j) {
    v[j] = xr[lane + 64 * j];
    sum += v[j].x + v[j].y + v[j].z + v[j].w;
    sq += v[j].x * v[j].x + v[j].y * v[j].y + v[j].z * v[j].z + v[j].w * v[j].w;
  }
#pragma unroll
  for (int off = 32; off; off >>= 1) {
    sum += __shfl_xor(sum, off);
    sq += __shfl_xor(sq, off);
  }
  float mu = sum * (1.f / (float)H_);
  float rstd = rsqrtf(sq * (1.f / (float)H_) - mu * mu + 1e-5f);
  ushort4* yr = reinterpret_cast<ushort4*>(y + (size_t)row * H_);
#pragma unroll
  for (int j = 0; j < 4; ++j) {
    int c4 = lane + 64 * j;
    float4 sc = reinterpret_cast<const float4*>(s)[c4];
    float4 bc = reinterpret_cast<const float4*>(bb)[c4];
    ushort4 o;
    o.x = f2bf((v[j].x - mu) * rstd * sc.x + bc.x);
    o.y = f2bf((v[j].y - mu) * rstd * sc.y + bc.y);
    o.z = f2bf((v[j].z - mu) * rstd * sc.z + bc.z);
    o.w = f2bf((v[j].w - mu) * rstd * sc.w + bc.w);
    yr[c4] = o;
  }
}

// ---------- bf16 MFMA GEMM ----------
// Y[b][o][l] = sum_c W[o][c] * X[b][l][c] (+bias[o]). A-frag rows = l, B-frag
// rows = o. Tile BM=128(l) x BN=64(o) x BK=32, 4 waves.
// MODE 0: Y[b,o,l] = val (ldo/ooff).
// MODE 1: nodes fp32 [B,L,H]: Y[b,l,o] += leaky(val); Ybf[b,l,o] = bf16(sum).
// MODE 2: scalar stores with ldo/ooff (kkb [b,o,p]).
template <int MODE>
__global__ __launch_bounds__(256) void k_gemm_bf(const u16* __restrict__ W,
                                                 const float* __restrict__ bias,
                                                 const u16* __restrict__ X,
                                                 float* __restrict__ Y,
                                                 u16* __restrict__ Ybf,
                                                 int ldo, int ooff) {
  __shared__ __align__(16) u16 sA[128 * 32];
  __shared__ __align__(16) u16 sB[64 * 32];
  const int b = blockIdx.z;
  const int bm = blockIdx.x * 128;  // l
  const int bn = blockIdx.y * 64;   // o
  const int t = threadIdx.x;
  const int w = t >> 6, lane = t & 63;
  const int wm = w >> 1, wn = w & 1;
  const int r4 = lane >> 2, slot = lane & 3;

  const u16* Xb = X + ((size_t)b * 1024 + bm) * 1024;

  const int rowA0 = w * 16 + r4;
  const int rowA1 = 64 + rowA0;
  const int colA0 = ((slot ^ ((rowA0 >> 1) & 3)) << 3);
  const int colA1 = ((slot ^ ((rowA1 >> 1) & 3)) << 3);
  const int rowB = w * 16 + r4;
  const int colB = ((slot ^ ((rowB >> 1) & 3)) << 3);
  const u16* gA0 = Xb + (size_t)rowA0 * 1024 + colA0;
  const u16* gA1 = Xb + (size_t)rowA1 * 1024 + colA1;
  const u16* gB = W + (size_t)(bn + rowB) * 1024 + colB;
  u16* lA0 = sA + (size_t)w * 512;
  u16* lA1 = sA + (size_t)(4 + w) * 512;
  u16* lB = sB + (size_t)w * 512;

  const int kb_ = lane >> 4;
  const int kidx = ((kb_ ^ ((lane >> 1) & 3)) << 3);
  const int rA = wm * 64 + (lane & 15);
  const int rB2 = wn * 32 + (lane & 15);

  f32x4 acc[4][2];
#pragma unroll
  for (int mf = 0; mf < 4; ++mf)
#pragma unroll
    for (int nf = 0; nf < 2; ++nf) acc[mf][nf] = f32x4{0.f, 0.f, 0.f, 0.f};

  for (int ck = 0; ck < 1024; ck += 32) {
    gl_lds16(gA0, lA0);
    gl_lds16(gA1, lA1);
    gl_lds16(gB, lB);
    gA0 += 32; gA1 += 32; gB += 32;
    __syncthreads();
    short8 af[4], bfr[2];
#pragma unroll
    for (int mf = 0; mf < 4; ++mf)
      af[mf] = *reinterpret_cast<const short8*>(&sA[(rA + mf * 16) * 32 + kidx]);
#pragma unroll
    for (int nf = 0; nf < 2; ++nf)
      bfr[nf] = *reinterpret_cast<const short8*>(&sB[(rB2 + nf * 16) * 32 + kidx]);
#pragma unroll
    for (int mf = 0; mf < 4; ++mf)
#pragma unroll
      for (int nf = 0; nf < 2; ++nf)
        acc[mf][nf] = __builtin_amdgcn_mfma_f32_16x16x32_bf16(af[mf], bfr[nf], acc[mf][nf], 0, 0, 0);
    __syncthreads();
  }

#pragma unroll
  for (int nf = 0; nf < 2; ++nf) {
    int o = bn + wn * 32 + nf * 16 + (lane & 15);
    float bs = bias[o];
#pragma unroll
    for (int mf = 0; mf < 4; ++mf) {
      int l = bm + wm * 64 + mf * 16 + ((lane >> 4) << 2);
      f32x4 v = acc[mf][nf];
      if (MODE == 0) {
        size_t yi = ((size_t)(b * 1024 + o)) * (size_t)ldo + ooff + l;
        f32x4 ov = {v[0] + bs, v[1] + bs, v[2] + bs, v[3] + bs};
        *reinterpret_cast<f32x4*>(&Y[yi]) = ov;
      } else if (MODE == 1) {
#pragma unroll
        for (int r = 0; r < 4; ++r) {
          size_t ni = ((size_t)(b * 1024 + l + r)) * 1024 + o;
          float val = v[r] + bs;
          val = val > 0.f ? val : 0.01f * val;
          float nv = Y[ni] + val;
          Y[ni] = nv;
          Ybf[ni] = f2bf(nv);
        }
      } else {
        size_t yi = ((size_t)(b * 1024 + o)) * (size_t)ldo + ooff + l;
#pragma unroll
        for (int r = 0; r < 4; ++r) Y[yi + r] = v[r] + bs;
      }
    }
  }
}

// ---------- matvec: wave per output ----------
__global__ __launch_bounds__(256) void k_matvec(const float* __restrict__ W,
                                                const float* __restrict__ bias,
                                                const float* __restrict__ x,
                                                float* __restrict__ y,
                                                long strideB, long strideO, int leaky) {
  int b = blockIdx.y;
  int o = blockIdx.x * 4 + (threadIdx.x >> 6);
  int lane = threadIdx.x & 63;
  const float* wr = W + (size_t)o * 1024;
  const float* xb = x + (size_t)b * 1024;
  float acc = 0.f;
  for (int c = lane; c < 1024; c += 64) acc += wr[c] * xb[c];
#pragma unroll
  for (int off = 32; off; off >>= 1) acc += __shfl_xor(acc, off);
  if (lane == 0) {
    acc += bias[o];
    if (leaky) acc = acc > 0.f ? acc : 0.01f * acc;
    y[(size_t)b * strideB + (size_t)o * strideO] = acc;
  }
}

// ---------- msa1 ring attention: 4 lanes per l, 16 d each ----------
__global__ __launch_bounds__(256) void k_msa1(const float* __restrict__ q,
                                              const float* __restrict__ k,
                                              const float* __restrict__ v,
                                              const float* __restrict__ ke,
                                              const float* __restrict__ ve,
                                              const float* __restrict__ rk,
                                              const float* __restrict__ rv,
                                              u16* __restrict__ attbf) {
  int t = threadIdx.x;
  int l = blockIdx.x * 64 + (t >> 2);
  int dg = t & 3;
  int n = blockIdx.y, b = blockIdx.z;
  size_t rb = (size_t)((b * NH_ + n) * HD_) + dg * 16;
  size_t base = rb * (size_t)L_ + l;
  bool inner = (l >= 2) && (l <= L_ - 3);
  float s[7] = {0.f, 0.f, 0.f, 0.f, 0.f, 0.f, 0.f};
  for (int i = 0; i < 16; ++i) {
    size_t off = base + (size_t)i * L_;
    float qd = q[off];
    const float* kd = k + off;
    s[5] = fmaf(qd, ke[off], s[5]);
    s[6] = fmaf(qd, rk[rb + i], s[6]);
    if (inner) {
      s[0] = fmaf(qd, kd[-2], s[0]);
      s[1] = fmaf(qd, kd[-1], s[1]);
      s[2] = fmaf(qd, kd[0], s[2]);
      s[3] = fmaf(qd, kd[1], s[3]);
      s[4] = fmaf(qd, kd[2], s[4]);
    } else {
#pragma unroll
      for (int u = 0; u < 5; ++u) {
        int lk = l + u - 2;
        if (lk >= 0 && lk < L_) s[u] = fmaf(qd, kd[u - 2], s[u]);
      }
    }
  }
#pragma unroll
  for (int u = 0; u < 7; ++u) {
    s[u] += __shfl_xor(s[u], 1);
    s[u] += __shfl_xor(s[u], 2);
  }
  float m = -1e30f;
#pragma unroll
  for (int u = 0; u < 7; ++u) {
    s[u] *= 0.125f;
    m = fmaxf(m, s[u]);
  }
  float e[7], tot = 0.f;
#pragma unroll
  for (int u = 0; u < 7; ++u) {
    e[u] = expf(s[u] - m);
    tot += e[u];
  }
  float inv = 1.f / tot;
#pragma unroll
  for (int u = 0; u < 7; ++u) e[u] *= inv;
  u16 outv[16];
  for (int i = 0; i < 16; ++i) {
    size_t off = base + (size_t)i * L_;
    const float* vd = v + off;
    float a = e[5] * ve[off] + e[6] * rv[rb + i];
    if (inner) {
      a = fmaf(e[0], vd[-2], a);
      a = fmaf(e[1], vd[-1], a);
      a = fmaf(e[2], vd[0], a);
      a = fmaf(e[3], vd[1], a);
      a = fmaf(e[4], vd[2], a);
    } else {
#pragma unroll
      for (int u = 0; u < 5; ++u) {
        int lk = l + u - 2;
        if (lk >= 0 && lk < L_) a = fmaf(e[u], vd[u - 2], a);
      }
    }
    outv[i] = f2bf(a);
  }
  u16* dst = attbf + ((size_t)b * L_ + l) * 1024 + n * 64 + dg * 16;
  reinterpret_cast<uint4*>(dst)[0] = reinterpret_cast<uint4*>(outv)[0];
  reinterpret_cast<uint4*>(dst)[1] = reinterpret_cast<uint4*>(outv)[1];
}

// ---------- msa2 star attention: 1024 threads per (b,n); v = k (faithful) ----------
__global__ __launch_bounds__(1024) void k_msa2(const float* __restrict__ rq,
                                               const float* __restrict__ kk,
                                               const int* __restrict__ mask,
                                               float* __restrict__ satt) {
  int n = blockIdx.x, b = blockIdx.y;
  int t = threadIdx.x;
  __shared__ float sq_[HD_];
  __shared__ float se[L_ + 1];
  __shared__ float swsum[16];
  __shared__ float stot;
  size_t rb = (size_t)(b * NH_ + n) * HD_;
  if (t < HD_) sq_[t] = rq[rb + t];
  __syncthreads();
  const float* kb = kk + rb * (size_t)(L_ + 1);
  float ls = 0.f;
  for (int p = t; p < L_ + 1; p += 1024) {
    float e;
    if (p > 0 && mask[b * L_ + p - 1] == 0) {
      e = 0.f;
    } else {
      float acc = 0.f;
      for (int d = 0; d < HD_; ++d) acc = fmaf(sq_[d], kb[(size_t)d * (L_ + 1) + p], acc);
      e = expf(acc * 0.125f);
    }
    se[p] = e;
    ls += e;
  }
  int lane = t & 63, w = t >> 6;
#pragma unroll
  for (int off = 32; off; off >>= 1) ls += __shfl_xor(ls, off);
  if (lane == 0) swsum[w] = ls;
  __syncthreads();
  if (t == 0) {
    float tot = 0.f;
    for (int j = 0; j < 16; ++j) tot += swsum[j];
    stot = 1.f / tot;
  }
  __syncthreads();
  float inv = stot;
  float acc[4] = {0.f, 0.f, 0.f, 0.f};
  const float* kw = kb + (size_t)(w * 4) * (L_ + 1);
  for (int p = lane; p < L_ + 1; p += 64) {
    float e = se[p];
#pragma unroll
    for (int j = 0; j < 4; ++j) acc[j] = fmaf(e, kw[(size_t)j * (L_ + 1) + p], acc[j]);
  }
#pragma unroll
  for (int j = 0; j < 4; ++j) {
    float a = acc[j];
#pragma unroll
    for (int off = 32; off; off >>= 1) a += __shfl_xor(a, off);
    if (lane == 0) satt[rb + w * 4 + j] = a * inv;
  }
}

// ---------- zero nodes rows at padding positions; nodes [B,L,H] ----------
__global__ void k_maskzero(float* __restrict__ nodes, const int* __restrict__ mask) {
  int i = blockIdx.x * 256 + threadIdx.x;  // float4 index over B*L*H/4
  int row = i >> 8;
  int b = row >> 10, l = row & 1023;
  if (mask[b * L_ + l] == 0) reinterpret_cast<float4*>(nodes)[i] = float4{0.f, 0.f, 0.f, 0.f};
}

__global__ void k_copy_relay(const float* __restrict__ relay, float* __restrict__ out) {
  int i = blockIdx.x * 256 + threadIdx.x;
  out[i] = relay[i];
}

}  // namespace

extern "C" void kernel_launch(void* const* d_in, const int* in_sizes, int n_in,
                              void* d_out, int out_size, void* d_ws, size_t ws_size,
                              hipStream_t stream) {
  (void)in_sizes; (void)n_in; (void)out_size; (void)ws_size;
  const float* data = (const float*)d_in[0];
  const int* mask = (const int*)d_in[1];
  const float* ln_s = (const float*)d_in[2];
  const float* ln_b = (const float*)d_in[3];
  const float* rwq = (const float*)d_in[4];
  const float* rwq_b = (const float*)d_in[5];
  const float* rwk = (const float*)d_in[6];
  const float* rwk_b = (const float*)d_in[7];
  const float* rwv = (const float*)d_in[8];
  const float* rwv_b = (const float*)d_in[9];
  const float* rwo = (const float*)d_in[10];
  const float* rwo_b = (const float*)d_in[11];
  const float* swq = (const float*)d_in[12];
  const float* swq_b = (const float*)d_in[13];
  const float* swk = (const float*)d_in[14];
  const float* swk_b = (const float*)d_in[15];
  const float* swo = (const float*)d_in[16];
  const float* swo_b = (const float*)d_in[17];
  float* out = (float*)d_out;

  const size_t SZ = (size_t)B_ * ND_ * L_;  // 4M
  float* f = (float*)d_ws;
  float* nodes = f; f += SZ;           // fp32 [B,L,H]
  float* q = f; f += SZ;               // [B,ND,L]
  float* kbuf = f; f += SZ;
  float* vbuf = f; f += SZ;
  float* ke = f; f += SZ;
  float* ve = f; f += SZ;
  float* kkb = f; f += (size_t)B_ * ND_ * (L_ + 1);
  float* part = f; f += (size_t)B_ * 8 * H_;
  float* relay = f; f += B_ * H_;
  float* rk = f; f += B_ * ND_;
  float* rv = f; f += B_ * ND_;
  float* rq = f; f += B_ * ND_;
  float* satt = f; f += B_ * ND_;
  u16* u = (u16*)f;
  u16* xn_bf = u; u += SZ;             // [B,L,H]
  u16* embs_bf = u; u += SZ;           // [B,L,H] = bf16(data)
  u16* att_bf = u; u += SZ;            // [B,L,H]
  u16* nodes_bf = u; u += SZ;          // [B,L,H]
  u16* wq_bf = u; u += SZ;
  u16* wk_bf = u; u += SZ;
  u16* wv_bf = u; u += SZ;
  u16* wo_bf = u; u += SZ;
  u16* swk_bf = u; u += SZ;

  k_f2bf<<<4096, 256, 0, stream>>>(data, embs_bf, (int)(SZ / 4));
  k_f2bf<<<4096, 256, 0, stream>>>(rwq, wq_bf, (int)(SZ / 4));
  k_f2bf<<<4096, 256, 0, stream>>>(rwk, wk_bf, (int)(SZ / 4));
  k_f2bf<<<4096, 256, 0, stream>>>(rwv, wv_bf, (int)(SZ / 4));
  k_f2bf<<<4096, 256, 0, stream>>>(rwo, wo_bf, (int)(SZ / 4));
  k_f2bf<<<4096, 256, 0, stream>>>(swk, swk_bf, (int)(SZ / 4));

  k_copy4<<<4096, 256, 0, stream>>>(data, nodes);
  k_relay_part<<<dim3(H_ / 256, 8, B_), 256, 0, stream>>>(data, part);
  k_relay_reduce<<<dim3((B_ * H_) / 256), 256, 0, stream>>>(part, relay);

  dim3 gg(8, 16, B_);
  dim3 gmv(256, B_);
  for (int i = 0; i < ITERS_; ++i) {
    const u16* wq_i = wq_bf + (size_t)i * ND_ * H_;
    const u16* wk_i = wk_bf + (size_t)i * ND_ * H_;
    const u16* wv_i = wv_bf + (size_t)i * ND_ * H_;
    const u16* wo_i = wo_bf + (size_t)i * H_ * ND_;
    const u16* sk_i = swk_bf + (size_t)i * ND_ * H_;

    k_layernorm_bf<<<dim3(B_ * L_ / 4), 256, 0, stream>>>(nodes, ln_s + i * H_, ln_b + i * H_, xn_bf);
    k_gemm_bf<0><<<gg, 256, 0, stream>>>(wq_i, rwq_b + i * ND_, xn_bf, q, nullptr, L_, 0);
    k_gemm_bf<0><<<gg, 256, 0, stream>>>(wk_i, rwk_b + i * ND_, xn_bf, kbuf, nullptr, L_, 0);
    k_gemm_bf<0><<<gg, 256, 0, stream>>>(wv_i, rwv_b + i * ND_, xn_bf, vbuf, nullptr, L_, 0);
    k_gemm_bf<0><<<gg, 256, 0, stream>>>(wk_i, rwk_b + i * ND_, embs_bf, ke, nullptr, L_, 0);
    k_gemm_bf<0><<<gg, 256, 0, stream>>>(wv_i, rwv_b + i * ND_, embs_bf, ve, nullptr, L_, 0);
    k_matvec<<<gmv, 256, 0, stream>>>(rwk + (size_t)i * ND_ * H_, rwk_b + i * ND_, relay, rk, ND_, 1, 0);
    k_matvec<<<gmv, 256, 0, stream>>>(rwv + (size_t)i * ND_ * H_, rwv_b + i * ND_, relay, rv, ND_, 1, 0);
    k_msa1<<<dim3(L_ / 64, NH_, B_), 256, 0, stream>>>(q, kbuf, vbuf, ke, ve, rk, rv, att_bf);
    // nodes += leaky(Wo @ att + bo); nodes_bf = bf16(nodes)   (nodes [B,L,H])
    k_gemm_bf<1><<<gg, 256, 0, stream>>>(wo_i, rwo_b + i * H_, att_bf, nodes, nodes_bf, 0, 0);
    // star attention (old relay; nodes before zeroing)
    k_matvec<<<gmv, 256, 0, stream>>>(swq + (size_t)i * ND_ * H_, swq_b + i * ND_, relay, rq, ND_, 1, 0);
    k_matvec<<<gmv, 256, 0, stream>>>(swk + (size_t)i * ND_ * H_, swk_b + i * ND_, relay, kkb,
                                      (long)ND_ * (L_ + 1), L_ + 1, 0);
    k_gemm_bf<2><<<gg, 256, 0, stream>>>(sk_i, swk_b + i * ND_, nodes_bf, kkb, nullptr, L_ + 1, 1);
    k_msa2<<<dim3(NH_, B_), 1024, 0, stream>>>(rq, kkb, mask, satt);
    k_matvec<<<gmv, 256, 0, stream>>>(swo + (size_t)i * H_ * ND_, swo_b + i * H_, satt, relay, H_, 1, 1);
    k_maskzero<<<(B_ * L_ * H_ / 4) / 256, 256, 0, stream>>>(nodes, mask);
  }
  k_copy4<<<4096, 256, 0, stream>>>(nodes, out);
  k_copy_relay<<<dim3((B_ * H_) / 256), 256, 0, stream>>>(relay, out + (size_t)B_ * L_ * H_);
}

// Round 4
// 916.461 us; speedup vs baseline: 5.6810x; 1.2889x over previous
//
#include <hip/hip_runtime.h>
#include <math.h>

namespace {

constexpr int B_ = 4, L_ = 1024, H_ = 1024, NH_ = 16, HD_ = 64, ND_ = 1024, ITERS_ = 4;

typedef unsigned short u16;
typedef __attribute__((ext_vector_type(8))) short short8;
typedef __attribute__((ext_vector_type(4))) float f32x4;

__device__ inline u16 f2bf(float f) {
  unsigned u = __builtin_bit_cast(unsigned, f);
  u += 0x7FFFu + ((u >> 16) & 1u);
  return (u16)(u >> 16);
}
__device__ inline float bf2f(u16 v) {
  unsigned u = ((unsigned)v) << 16;
  return __builtin_bit_cast(float, u);
}

__device__ inline void gl_lds16(const u16* g, u16* l) {
  __builtin_amdgcn_global_load_lds((const __attribute__((address_space(1))) void*)g,
                                   (__attribute__((address_space(3))) void*)l, 16, 0, 0);
}

// ---------- fp32 -> bf16 conversion ----------
__global__ void k_f2bf(const float* __restrict__ src, u16* __restrict__ dst, int n4) {
  int i = blockIdx.x * 256 + threadIdx.x;
  if (i < n4) {
    float4 v = reinterpret_cast<const float4*>(src)[i];
    ushort4 o;
    o.x = f2bf(v.x); o.y = f2bf(v.y); o.z = f2bf(v.z); o.w = f2bf(v.w);
    reinterpret_cast<ushort4*>(dst)[i] = o;
  }
}

// ---------- float4 copy ----------
__global__ void k_copy4(const float* __restrict__ src, float* __restrict__ dst) {
  int i = blockIdx.x * 256 + threadIdx.x;
  reinterpret_cast<float4*>(dst)[i] = reinterpret_cast<const float4*>(src)[i];
}

// ---------- relay init ----------
__global__ void k_relay_part(const float* __restrict__ data, float* __restrict__ part) {
  int b = blockIdx.z, chunk = blockIdx.y;
  int c = blockIdx.x * 256 + threadIdx.x;
  const float* p = data + ((size_t)b * L_ + chunk * 128) * H_ + c;
  float acc = 0.f;
  for (int l = 0; l < 128; ++l) acc += p[(size_t)l * H_];
  part[((size_t)b * 8 + chunk) * H_ + c] = acc;
}
__global__ void k_relay_reduce(const float* __restrict__ part, float* __restrict__ relay) {
  int i = blockIdx.x * 256 + threadIdx.x;
  int b = i >> 10, c = i & 1023;
  float acc = 0.f;
  for (int j = 0; j < 8; ++j) acc += part[((size_t)b * 8 + j) * H_ + c];
  relay[i] = acc * (1.f / (float)L_);
}

// ---------- LayerNorm rows of [B,L,H] fp32 -> bf16 ----------
__global__ __launch_bounds__(256) void k_layernorm_bf(const float* __restrict__ x,
                                                      const float* __restrict__ s,
                                                      const float* __restrict__ bb,
                                                      u16* __restrict__ y) {
  int row = blockIdx.x * 4 + (threadIdx.x >> 6);
  int lane = threadIdx.x & 63;
  const float4* xr = reinterpret_cast<const float4*>(x + (size_t)row * H_);
  float4 v[4];
  float sum = 0.f, sq = 0.f;
#pragma unroll
  for (int j = 0; j < 4; ++j) {
    v[j] = xr[lane + 64 * j];
    sum += v[j].x + v[j].y + v[j].z + v[j].w;
    sq += v[j].x * v[j].x + v[j].y * v[j].y + v[j].z * v[j].z + v[j].w * v[j].w;
  }
#pragma unroll
  for (int off = 32; off; off >>= 1) {
    sum += __shfl_xor(sum, off);
    sq += __shfl_xor(sq, off);
  }
  float mu = sum * (1.f / (float)H_);
  float rstd = rsqrtf(sq * (1.f / (float)H_) - mu * mu + 1e-5f);
  ushort4* yr = reinterpret_cast<ushort4*>(y + (size_t)row * H_);
#pragma unroll
  for (int j = 0; j < 4; ++j) {
    int c4 = lane + 64 * j;
    float4 sc = reinterpret_cast<const float4*>(s)[c4];
    float4 bc = reinterpret_cast<const float4*>(bb)[c4];
    ushort4 o;
    o.x = f2bf((v[j].x - mu) * rstd * sc.x + bc.x);
    o.y = f2bf((v[j].y - mu) * rstd * sc.y + bc.y);
    o.z = f2bf((v[j].z - mu) * rstd * sc.z + bc.z);
    o.w = f2bf((v[j].w - mu) * rstd * sc.w + bc.w);
    yr[c4] = o;
  }
}

// ---------- swapped-operand MFMA GEMM: out bf16 [B,L,ND] ----------
// Y[which][b][l][o] = bf16(sum_c W[o][c] * X[b][l][c] + bias[o]).
// A = W (M=o), B = X (N=l): D col=lane&15 -> l, row -> 4 consecutive o.
// Tile 64(o) x 128(l) x BK=32; 4 waves (wm=o-half, wn=l-half).
// which = blockIdx.y>>4 selects weight/bias; Y offset which*B*L*ND.
__global__ __launch_bounds__(256) void k_gemm_wbf(const u16* __restrict__ W0,
                                                  const u16* __restrict__ W1,
                                                  const u16* __restrict__ W2,
                                                  const float* __restrict__ bias0,
                                                  const float* __restrict__ bias1,
                                                  const float* __restrict__ bias2,
                                                  const u16* __restrict__ X,
                                                  u16* __restrict__ Y) {
  __shared__ __align__(16) u16 sX[128 * 32];
  __shared__ __align__(16) u16 sW[64 * 32];
  const int b = blockIdx.z;
  const int bm = blockIdx.x * 128;  // l
  const int which = blockIdx.y >> 4;
  const int bn = (blockIdx.y & 15) * 64;  // o
  const u16* W = which == 0 ? W0 : (which == 1 ? W1 : W2);
  const float* bias = which == 0 ? bias0 : (which == 1 ? bias1 : bias2);
  u16* Yw = Y + (size_t)which * ((size_t)B_ * L_ * ND_);
  const int t = threadIdx.x;
  const int w = t >> 6, lane = t & 63;
  const int wm = w & 1, wn = w >> 1;
  const int r4 = lane >> 2, slot = lane & 3;

  const u16* Xb = X + ((size_t)b * 1024 + bm) * 1024;
  const int rowA0 = w * 16 + r4;
  const int rowA1 = 64 + rowA0;
  const int colA0 = ((slot ^ ((rowA0 >> 1) & 3)) << 3);
  const int colA1 = ((slot ^ ((rowA1 >> 1) & 3)) << 3);
  const int rowB = w * 16 + r4;
  const int colB = ((slot ^ ((rowB >> 1) & 3)) << 3);
  const u16* gA0 = Xb + (size_t)rowA0 * 1024 + colA0;
  const u16* gA1 = Xb + (size_t)rowA1 * 1024 + colA1;
  const u16* gB = W + (size_t)(bn + rowB) * 1024 + colB;
  u16* lA0 = sX + (size_t)w * 512;
  u16* lA1 = sX + (size_t)(4 + w) * 512;
  u16* lB = sW + (size_t)w * 512;

  const int kidx = (((lane >> 4) ^ ((lane >> 1) & 3)) << 3);
  const int rW = wm * 32 + (lane & 15);
  const int rX = wn * 64 + (lane & 15);

  f32x4 acc[2][4];
#pragma unroll
  for (int mo = 0; mo < 2; ++mo)
#pragma unroll
    for (int nl = 0; nl < 4; ++nl) acc[mo][nl] = f32x4{0.f, 0.f, 0.f, 0.f};

  for (int ck = 0; ck < 1024; ck += 32) {
    gl_lds16(gA0, lA0);
    gl_lds16(gA1, lA1);
    gl_lds16(gB, lB);
    gA0 += 32; gA1 += 32; gB += 32;
    __syncthreads();
    short8 aw[2], bx[4];
#pragma unroll
    for (int mo = 0; mo < 2; ++mo)
      aw[mo] = *reinterpret_cast<const short8*>(&sW[(rW + mo * 16) * 32 + kidx]);
#pragma unroll
    for (int nl = 0; nl < 4; ++nl)
      bx[nl] = *reinterpret_cast<const short8*>(&sX[(rX + nl * 16) * 32 + kidx]);
#pragma unroll
    for (int mo = 0; mo < 2; ++mo)
#pragma unroll
      for (int nl = 0; nl < 4; ++nl)
        acc[mo][nl] = __builtin_amdgcn_mfma_f32_16x16x32_bf16(aw[mo], bx[nl], acc[mo][nl], 0, 0, 0);
    __syncthreads();
  }

#pragma unroll
  for (int mo = 0; mo < 2; ++mo) {
    int o0 = bn + wm * 32 + mo * 16 + ((lane >> 4) << 2);
    float4 bs = *reinterpret_cast<const float4*>(bias + o0);
#pragma unroll
    for (int nl = 0; nl < 4; ++nl) {
      int l = bm + wn * 64 + nl * 16 + (lane & 15);
      f32x4 vv = acc[mo][nl];
      ushort4 ov;
      ov.x = f2bf(vv[0] + bs.x);
      ov.y = f2bf(vv[1] + bs.y);
      ov.z = f2bf(vv[2] + bs.z);
      ov.w = f2bf(vv[3] + bs.w);
      *reinterpret_cast<ushort4*>(&Yw[((size_t)(b * 1024 + l)) * 1024 + o0]) = ov;
    }
  }
}

// ---------- swapped-operand Wo GEMM: nodes[B,L,H] += leaky(val); nodes_bf = bf16 ----------
__global__ __launch_bounds__(256) void k_gemm_wo(const u16* __restrict__ W,
                                                 const float* __restrict__ bias,
                                                 const u16* __restrict__ X,
                                                 float* __restrict__ nodes,
                                                 u16* __restrict__ nodes_bf) {
  __shared__ __align__(16) u16 sX[128 * 32];
  __shared__ __align__(16) u16 sW[64 * 32];
  const int b = blockIdx.z;
  const int bm = blockIdx.x * 128;
  const int bn = blockIdx.y * 64;
  const int t = threadIdx.x;
  const int w = t >> 6, lane = t & 63;
  const int wm = w & 1, wn = w >> 1;
  const int r4 = lane >> 2, slot = lane & 3;

  const u16* Xb = X + ((size_t)b * 1024 + bm) * 1024;
  const int rowA0 = w * 16 + r4;
  const int rowA1 = 64 + rowA0;
  const int colA0 = ((slot ^ ((rowA0 >> 1) & 3)) << 3);
  const int colA1 = ((slot ^ ((rowA1 >> 1) & 3)) << 3);
  const int rowB = w * 16 + r4;
  const int colB = ((slot ^ ((rowB >> 1) & 3)) << 3);
  const u16* gA0 = Xb + (size_t)rowA0 * 1024 + colA0;
  const u16* gA1 = Xb + (size_t)rowA1 * 1024 + colA1;
  const u16* gB = W + (size_t)(bn + rowB) * 1024 + colB;
  u16* lA0 = sX + (size_t)w * 512;
  u16* lA1 = sX + (size_t)(4 + w) * 512;
  u16* lB = sW + (size_t)w * 512;

  const int kidx = (((lane >> 4) ^ ((lane >> 1) & 3)) << 3);
  const int rW = wm * 32 + (lane & 15);
  const int rX = wn * 64 + (lane & 15);

  f32x4 acc[2][4];
#pragma unroll
  for (int mo = 0; mo < 2; ++mo)
#pragma unroll
    for (int nl = 0; nl < 4; ++nl) acc[mo][nl] = f32x4{0.f, 0.f, 0.f, 0.f};

  for (int ck = 0; ck < 1024; ck += 32) {
    gl_lds16(gA0, lA0);
    gl_lds16(gA1, lA1);
    gl_lds16(gB, lB);
    gA0 += 32; gA1 += 32; gB += 32;
    __syncthreads();
    short8 aw[2], bx[4];
#pragma unroll
    for (int mo = 0; mo < 2; ++mo)
      aw[mo] = *reinterpret_cast<const short8*>(&sW[(rW + mo * 16) * 32 + kidx]);
#pragma unroll
    for (int nl = 0; nl < 4; ++nl)
      bx[nl] = *reinterpret_cast<const short8*>(&sX[(rX + nl * 16) * 32 + kidx]);
#pragma unroll
    for (int mo = 0; mo < 2; ++mo)
#pragma unroll
      for (int nl = 0; nl < 4; ++nl)
        acc[mo][nl] = __builtin_amdgcn_mfma_f32_16x16x32_bf16(aw[mo], bx[nl], acc[mo][nl], 0, 0, 0);
    __syncthreads();
  }

#pragma unroll
  for (int mo = 0; mo < 2; ++mo) {
    int o0 = bn + wm * 32 + mo * 16 + ((lane >> 4) << 2);
    float4 bs = *reinterpret_cast<const float4*>(bias + o0);
#pragma unroll
    for (int nl = 0; nl < 4; ++nl) {
      int l = bm + wn * 64 + nl * 16 + (lane & 15);
      size_t ni = ((size_t)(b * 1024 + l)) * 1024 + o0;
      float4 cur = *reinterpret_cast<const float4*>(&nodes[ni]);
      f32x4 vv = acc[mo][nl];
      float r0 = vv[0] + bs.x; r0 = cur.x + (r0 > 0.f ? r0 : 0.01f * r0);
      float r1 = vv[1] + bs.y; r1 = cur.y + (r1 > 0.f ? r1 : 0.01f * r1);
      float r2 = vv[2] + bs.z; r2 = cur.z + (r2 > 0.f ? r2 : 0.01f * r2);
      float r3 = vv[3] + bs.w; r3 = cur.w + (r3 > 0.f ? r3 : 0.01f * r3);
      *reinterpret_cast<float4*>(&nodes[ni]) = float4{r0, r1, r2, r3};
      ushort4 ov;
      ov.x = f2bf(r0); ov.y = f2bf(r1); ov.z = f2bf(r2); ov.w = f2bf(r3);
      *reinterpret_cast<ushort4*>(&nodes_bf[ni]) = ov;
    }
  }
}

// ---------- kkb GEMM (original orientation): kkb[b][o][1+l] = sum_c W[o][c]*X[b][l][c]+bias ----------
__global__ __launch_bounds__(256) void k_gemm_kkb(const u16* __restrict__ W,
                                                  const float* __restrict__ bias,
                                                  const u16* __restrict__ X,
                                                  float* __restrict__ Y) {
  __shared__ __align__(16) u16 sA[128 * 32];
  __shared__ __align__(16) u16 sB[64 * 32];
  const int b = blockIdx.z;
  const int bm = blockIdx.x * 128;  // l
  const int bn = blockIdx.y * 64;   // o
  const int t = threadIdx.x;
  const int w = t >> 6, lane = t & 63;
  const int wm = w >> 1, wn = w & 1;
  const int r4 = lane >> 2, slot = lane & 3;

  const u16* Xb = X + ((size_t)b * 1024 + bm) * 1024;
  const int rowA0 = w * 16 + r4;
  const int rowA1 = 64 + rowA0;
  const int colA0 = ((slot ^ ((rowA0 >> 1) & 3)) << 3);
  const int colA1 = ((slot ^ ((rowA1 >> 1) & 3)) << 3);
  const int rowB = w * 16 + r4;
  const int colB = ((slot ^ ((rowB >> 1) & 3)) << 3);
  const u16* gA0 = Xb + (size_t)rowA0 * 1024 + colA0;
  const u16* gA1 = Xb + (size_t)rowA1 * 1024 + colA1;
  const u16* gB = W + (size_t)(bn + rowB) * 1024 + colB;
  u16* lA0 = sA + (size_t)w * 512;
  u16* lA1 = sA + (size_t)(4 + w) * 512;
  u16* lB = sB + (size_t)w * 512;

  const int kidx = (((lane >> 4) ^ ((lane >> 1) & 3)) << 3);
  const int rA = wm * 64 + (lane & 15);
  const int rB2 = wn * 32 + (lane & 15);

  f32x4 acc[4][2];
#pragma unroll
  for (int mf = 0; mf < 4; ++mf)
#pragma unroll
    for (int nf = 0; nf < 2; ++nf) acc[mf][nf] = f32x4{0.f, 0.f, 0.f, 0.f};

  for (int ck = 0; ck < 1024; ck += 32) {
    gl_lds16(gA0, lA0);
    gl_lds16(gA1, lA1);
    gl_lds16(gB, lB);
    gA0 += 32; gA1 += 32; gB += 32;
    __syncthreads();
    short8 af[4], bfr[2];
#pragma unroll
    for (int mf = 0; mf < 4; ++mf)
      af[mf] = *reinterpret_cast<const short8*>(&sA[(rA + mf * 16) * 32 + kidx]);
#pragma unroll
    for (int nf = 0; nf < 2; ++nf)
      bfr[nf] = *reinterpret_cast<const short8*>(&sB[(rB2 + nf * 16) * 32 + kidx]);
#pragma unroll
    for (int mf = 0; mf < 4; ++mf)
#pragma unroll
      for (int nf = 0; nf < 2; ++nf)
        acc[mf][nf] = __builtin_amdgcn_mfma_f32_16x16x32_bf16(af[mf], bfr[nf], acc[mf][nf], 0, 0, 0);
    __syncthreads();
  }

#pragma unroll
  for (int nf = 0; nf < 2; ++nf) {
    int o = bn + wn * 32 + nf * 16 + (lane & 15);
    float bs = bias[o];
#pragma unroll
    for (int mf = 0; mf < 4; ++mf) {
      int l = bm + wm * 64 + mf * 16 + ((lane >> 4) << 2);
      size_t yi = ((size_t)(b * 1024 + o)) * (size_t)(L_ + 1) + 1 + l;
      f32x4 v = acc[mf][nf];
#pragma unroll
      for (int r = 0; r < 4; ++r) Y[yi + r] = v[r] + bs;
    }
  }
}

// ---------- matvec: wave per output ----------
__global__ __launch_bounds__(256) void k_matvec(const float* __restrict__ W,
                                                const float* __restrict__ bias,
                                                const float* __restrict__ x,
                                                float* __restrict__ y,
                                                long strideB, long strideO, int leaky) {
  int b = blockIdx.y;
  int o = blockIdx.x * 4 + (threadIdx.x >> 6);
  int lane = threadIdx.x & 63;
  const float* wr = W + (size_t)o * 1024;
  const float* xb = x + (size_t)b * 1024;
  float acc = 0.f;
  for (int c = lane; c < 1024; c += 64) acc += wr[c] * xb[c];
#pragma unroll
  for (int off = 32; off; off >>= 1) acc += __shfl_xor(acc, off);
  if (lane == 0) {
    acc += bias[o];
    if (leaky) acc = acc > 0.f ? acc : 0.01f * acc;
    y[(size_t)b * strideB + (size_t)o * strideO] = acc;
  }
}

// ---------- msa1 ring attention, bf16 [B,L,ND] inputs ----------
// thread = (l, head, dhalf): 32 contiguous d. 256 thr = 8 l x 16 head x 2 dh.
__global__ __launch_bounds__(256) void k_msa1(const u16* __restrict__ q,
                                              const u16* __restrict__ k,
                                              const u16* __restrict__ v,
                                              const u16* __restrict__ ke,
                                              const u16* __restrict__ ve,
                                              const float* __restrict__ rk,
                                              const float* __restrict__ rv,
                                              u16* __restrict__ attbf) {
  int t = threadIdx.x;
  int head = t & 15, dh = (t >> 4) & 1, lsub = t >> 5;
  int l = blockIdx.x * 8 + lsub;
  int b = blockIdx.z;
  size_t row = ((size_t)(b * 1024 + l)) * 1024 + head * 64 + dh * 32;
  size_t rbase = (size_t)b * 1024 + head * 64 + dh * 32;

  float qf[32];
  {
    const short8* qp = reinterpret_cast<const short8*>(q + row);
#pragma unroll
    for (int j = 0; j < 4; ++j) {
      short8 qv = qp[j];
#pragma unroll
      for (int e = 0; e < 8; ++e) qf[j * 8 + e] = bf2f((u16)qv[e]);
    }
  }
  float s[7];
#pragma unroll
  for (int u = 0; u < 5; ++u) {
    int lk = l + u - 2;
    float su = 0.f;
    if (lk >= 0 && lk < L_) {
      const short8* kp =
          reinterpret_cast<const short8*>(k + ((size_t)(b * 1024 + lk)) * 1024 + head * 64 + dh * 32);
#pragma unroll
      for (int j = 0; j < 4; ++j) {
        short8 kv = kp[j];
#pragma unroll
        for (int e = 0; e < 8; ++e) su = fmaf(qf[j * 8 + e], bf2f((u16)kv[e]), su);
      }
    }
    s[u] = su;
  }
  {
    float su = 0.f;
    const short8* kp = reinterpret_cast<const short8*>(ke + row);
#pragma unroll
    for (int j = 0; j < 4; ++j) {
      short8 kv = kp[j];
#pragma unroll
      for (int e = 0; e < 8; ++e) su = fmaf(qf[j * 8 + e], bf2f((u16)kv[e]), su);
    }
    s[5] = su;
  }
  {
    float su = 0.f;
    const float4* rp = reinterpret_cast<const float4*>(rk + rbase);
#pragma unroll
    for (int j = 0; j < 8; ++j) {
      float4 r4 = rp[j];
      su = fmaf(qf[j * 4 + 0], r4.x, su);
      su = fmaf(qf[j * 4 + 1], r4.y, su);
      su = fmaf(qf[j * 4 + 2], r4.z, su);
      su = fmaf(qf[j * 4 + 3], r4.w, su);
    }
    s[6] = su;
  }
  // combine d-halves (lane bit 4)
#pragma unroll
  for (int u = 0; u < 7; ++u) s[u] += __shfl_xor(s[u], 16);
  float m = -1e30f;
#pragma unroll
  for (int u = 0; u < 7; ++u) {
    s[u] *= 0.125f;
    m = fmaxf(m, s[u]);
  }
  float e[7], tot = 0.f;
#pragma unroll
  for (int u = 0; u < 7; ++u) {
    e[u] = expf(s[u] - m);
    tot += e[u];
  }
  float inv = 1.f / tot;
#pragma unroll
  for (int u = 0; u < 7; ++u) e[u] *= inv;

  float av[32];
  {
    const float4* rp = reinterpret_cast<const float4*>(rv + rbase);
#pragma unroll
    for (int j = 0; j < 8; ++j) {
      float4 r4 = rp[j];
      av[j * 4 + 0] = e[6] * r4.x;
      av[j * 4 + 1] = e[6] * r4.y;
      av[j * 4 + 2] = e[6] * r4.z;
      av[j * 4 + 3] = e[6] * r4.w;
    }
  }
  {
    const short8* vp = reinterpret_cast<const short8*>(ve + row);
#pragma unroll
    for (int j = 0; j < 4; ++j) {
      short8 vv = vp[j];
#pragma unroll
      for (int ee = 0; ee < 8; ++ee) av[j * 8 + ee] = fmaf(e[5], bf2f((u16)vv[ee]), av[j * 8 + ee]);
    }
  }
#pragma unroll
  for (int u = 0; u < 5; ++u) {
    int lk = l + u - 2;
    if (lk >= 0 && lk < L_) {
      const short8* vp =
          reinterpret_cast<const short8*>(v + ((size_t)(b * 1024 + lk)) * 1024 + head * 64 + dh * 32);
#pragma unroll
      for (int j = 0; j < 4; ++j) {
        short8 vv = vp[j];
#pragma unroll
        for (int ee = 0; ee < 8; ++ee) av[j * 8 + ee] = fmaf(e[u], bf2f((u16)vv[ee]), av[j * 8 + ee]);
      }
    }
  }
  u16 ob[32];
#pragma unroll
  for (int j = 0; j < 32; ++j) ob[j] = f2bf(av[j]);
  uint4* d4 = reinterpret_cast<uint4*>(attbf + row);
  const uint4* s4 = reinterpret_cast<const uint4*>(ob);
#pragma unroll
  for (int j = 0; j < 4; ++j) d4[j] = s4[j];
}

// ---------- msa2 star attention (v = k, faithful) ----------
__global__ __launch_bounds__(1024) void k_msa2(const float* __restrict__ rq,
                                               const float* __restrict__ kk,
                                               const int* __restrict__ mask,
                                               float* __restrict__ satt) {
  int n = blockIdx.x, b = blockIdx.y;
  int t = threadIdx.x;
  __shared__ float sq_[HD_];
  __shared__ float se[L_ + 1];
  __shared__ float swsum[16];
  __shared__ float stot;
  size_t rb = (size_t)(b * NH_ + n) * HD_;
  if (t < HD_) sq_[t] = rq[rb + t];
  __syncthreads();
  const float* kb = kk + rb * (size_t)(L_ + 1);
  float ls = 0.f;
  for (int p = t; p < L_ + 1; p += 1024) {
    float e;
    if (p > 0 && mask[b * L_ + p - 1] == 0) {
      e = 0.f;
    } else {
      float acc = 0.f;
      for (int d = 0; d < HD_; ++d) acc = fmaf(sq_[d], kb[(size_t)d * (L_ + 1) + p], acc);
      e = expf(acc * 0.125f);
    }
    se[p] = e;
    ls += e;
  }
  int lane = t & 63, w = t >> 6;
#pragma unroll
  for (int off = 32; off; off >>= 1) ls += __shfl_xor(ls, off);
  if (lane == 0) swsum[w] = ls;
  __syncthreads();
  if (t == 0) {
    float tot = 0.f;
    for (int j = 0; j < 16; ++j) tot += swsum[j];
    stot = 1.f / tot;
  }
  __syncthreads();
  float inv = stot;
  float acc[4] = {0.f, 0.f, 0.f, 0.f};
  const float* kw = kb + (size_t)(w * 4) * (L_ + 1);
  for (int p = lane; p < L_ + 1; p += 64) {
    float e = se[p];
#pragma unroll
    for (int j = 0; j < 4; ++j) acc[j] = fmaf(e, kw[(size_t)j * (L_ + 1) + p], acc[j]);
  }
#pragma unroll
  for (int j = 0; j < 4; ++j) {
    float a = acc[j];
#pragma unroll
    for (int off = 32; off; off >>= 1) a += __shfl_xor(a, off);
    if (lane == 0) satt[rb + w * 4 + j] = a * inv;
  }
}

// ---------- zero nodes rows at padding positions ----------
__global__ void k_maskzero(float* __restrict__ nodes, const int* __restrict__ mask) {
  int i = blockIdx.x * 256 + threadIdx.x;
  int row = i >> 8;
  int b = row >> 10, l = row & 1023;
  if (mask[b * L_ + l] == 0) reinterpret_cast<float4*>(nodes)[i] = float4{0.f, 0.f, 0.f, 0.f};
}

__global__ void k_copy_relay(const float* __restrict__ relay, float* __restrict__ out) {
  int i = blockIdx.x * 256 + threadIdx.x;
  out[i] = relay[i];
}

}  // namespace

extern "C" void kernel_launch(void* const* d_in, const int* in_sizes, int n_in,
                              void* d_out, int out_size, void* d_ws, size_t ws_size,
                              hipStream_t stream) {
  (void)in_sizes; (void)n_in; (void)out_size; (void)ws_size;
  const float* data = (const float*)d_in[0];
  const int* mask = (const int*)d_in[1];
  const float* ln_s = (const float*)d_in[2];
  const float* ln_b = (const float*)d_in[3];
  const float* rwq = (const float*)d_in[4];
  const float* rwq_b = (const float*)d_in[5];
  const float* rwk = (const float*)d_in[6];
  const float* rwk_b = (const float*)d_in[7];
  const float* rwv = (const float*)d_in[8];
  const float* rwv_b = (const float*)d_in[9];
  const float* rwo = (const float*)d_in[10];
  const float* rwo_b = (const float*)d_in[11];
  const float* swq = (const float*)d_in[12];
  const float* swq_b = (const float*)d_in[13];
  const float* swk = (const float*)d_in[14];
  const float* swk_b = (const float*)d_in[15];
  const float* swo = (const float*)d_in[16];
  const float* swo_b = (const float*)d_in[17];
  float* out = (float*)d_out;

  const size_t SZ = (size_t)B_ * ND_ * L_;  // 4M elements
  float* f = (float*)d_ws;
  float* nodes = f; f += SZ;                       // fp32 [B,L,H]
  float* kkb = f; f += (size_t)B_ * ND_ * (L_ + 1);
  float* part = f; f += (size_t)B_ * 8 * H_;
  float* relay = f; f += B_ * H_;
  float* rk = f; f += B_ * ND_;
  float* rv = f; f += B_ * ND_;
  float* rq = f; f += B_ * ND_;
  float* satt = f; f += B_ * ND_;
  u16* u = (u16*)f;
  u16* xn_bf = u; u += SZ;      // [B,L,H]
  u16* embs_bf = u; u += SZ;    // [B,L,H]
  u16* att_bf = u; u += SZ;     // [B,L,ND]
  u16* nodes_bf = u; u += SZ;   // [B,L,H]
  u16* qkv_bf = u; u += 3 * SZ; // [3][B,L,ND]
  u16* keve_bf = u; u += 2 * SZ;// [2][B,L,ND]
  u16* wq_bf = u; u += SZ;
  u16* wk_bf = u; u += SZ;
  u16* wv_bf = u; u += SZ;
  u16* wo_bf = u; u += SZ;
  u16* swk_bf = u; u += SZ;

  k_f2bf<<<4096, 256, 0, stream>>>(data, embs_bf, (int)(SZ / 4));
  k_f2bf<<<4096, 256, 0, stream>>>(rwq, wq_bf, (int)(SZ / 4));
  k_f2bf<<<4096, 256, 0, stream>>>(rwk, wk_bf, (int)(SZ / 4));
  k_f2bf<<<4096, 256, 0, stream>>>(rwv, wv_bf, (int)(SZ / 4));
  k_f2bf<<<4096, 256, 0, stream>>>(rwo, wo_bf, (int)(SZ / 4));
  k_f2bf<<<4096, 256, 0, stream>>>(swk, swk_bf, (int)(SZ / 4));

  k_copy4<<<4096, 256, 0, stream>>>(data, nodes);
  k_relay_part<<<dim3(H_ / 256, 8, B_), 256, 0, stream>>>(data, part);
  k_relay_reduce<<<dim3((B_ * H_) / 256), 256, 0, stream>>>(part, relay);

  dim3 gmv(256, B_);
  for (int i = 0; i < ITERS_; ++i) {
    const u16* wq_i = wq_bf + (size_t)i * ND_ * H_;
    const u16* wk_i = wk_bf + (size_t)i * ND_ * H_;
    const u16* wv_i = wv_bf + (size_t)i * ND_ * H_;
    const u16* wo_i = wo_bf + (size_t)i * H_ * ND_;
    const u16* sk_i = swk_bf + (size_t)i * ND_ * H_;

    k_layernorm_bf<<<dim3(B_ * L_ / 4), 256, 0, stream>>>(nodes, ln_s + i * H_, ln_b + i * H_, xn_bf);
    // q,k,v in one dispatch
    k_gemm_wbf<<<dim3(8, 48, B_), 256, 0, stream>>>(wq_i, wk_i, wv_i,
                                                    rwq_b + i * ND_, rwk_b + i * ND_, rwv_b + i * ND_,
                                                    xn_bf, qkv_bf);
    // ke,ve in one dispatch
    k_gemm_wbf<<<dim3(8, 32, B_), 256, 0, stream>>>(wk_i, wv_i, nullptr,
                                                    rwk_b + i * ND_, rwv_b + i * ND_, nullptr,
                                                    embs_bf, keve_bf);
    k_matvec<<<gmv, 256, 0, stream>>>(rwk + (size_t)i * ND_ * H_, rwk_b + i * ND_, relay, rk, ND_, 1, 0);
    k_matvec<<<gmv, 256, 0, stream>>>(rwv + (size_t)i * ND_ * H_, rwv_b + i * ND_, relay, rv, ND_, 1, 0);
    k_msa1<<<dim3(L_ / 8, 1, B_), 256, 0, stream>>>(qkv_bf, qkv_bf + SZ, qkv_bf + 2 * SZ,
                                                    keve_bf, keve_bf + SZ, rk, rv, att_bf);
    k_gemm_wo<<<dim3(8, 16, B_), 256, 0, stream>>>(wo_i, rwo_b + i * H_, att_bf, nodes, nodes_bf);
    // star attention (old relay; nodes before zeroing)
    k_matvec<<<gmv, 256, 0, stream>>>(swq + (size_t)i * ND_ * H_, swq_b + i * ND_, relay, rq, ND_, 1, 0);
    k_matvec<<<gmv, 256, 0, stream>>>(swk + (size_t)i * ND_ * H_, swk_b + i * ND_, relay, kkb,
                                      (long)ND_ * (L_ + 1), L_ + 1, 0);
    k_gemm_kkb<<<dim3(8, 16, B_), 256, 0, stream>>>(sk_i, swk_b + i * ND_, nodes_bf, kkb);
    k_msa2<<<dim3(NH_, B_), 1024, 0, stream>>>(rq, kkb, mask, satt);
    k_matvec<<<gmv, 256, 0, stream>>>(swo + (size_t)i * H_ * ND_, swo_b + i * H_, satt, relay, H_, 1, 1);
    k_maskzero<<<(B_ * L_ * H_ / 4) / 256, 256, 0, stream>>>(nodes, mask);
  }
  k_copy4<<<4096, 256, 0, stream>>>(nodes, out);
  k_copy_relay<<<dim3((B_ * H_) / 256), 256, 0, stream>>>(relay, out + (size_t)B_ * L_ * H_);
}

// Round 6
// 767.828 us; speedup vs baseline: 6.7807x; 1.1936x over previous
//
#include <hip/hip_runtime.h>
#include <math.h>

namespace {

constexpr int B_ = 4, L_ = 1024, H_ = 1024, NH_ = 16, HD_ = 64, ND_ = 1024, ITERS_ = 4;

typedef unsigned short u16;
typedef __attribute__((ext_vector_type(8))) short short8;
typedef __attribute__((ext_vector_type(4))) float f32x4;

__device__ inline u16 f2bf(float f) {
  unsigned u = __builtin_bit_cast(unsigned, f);
  u += 0x7FFFu + ((u >> 16) & 1u);
  return (u16)(u >> 16);
}
__device__ inline float bf2f(u16 v) {
  unsigned u = ((unsigned)v) << 16;
  return __builtin_bit_cast(float, u);
}

__device__ inline void gl_lds16(const u16* g, u16* l) {
  __builtin_amdgcn_global_load_lds((const __attribute__((address_space(1))) void*)g,
                                   (__attribute__((address_space(3))) void*)l, 16, 0, 0);
}

// ---------- prep: 6 f2bf conversions + nodes copy, one dispatch ----------
__global__ void k_prep(const float* __restrict__ data, const float* __restrict__ rwq,
                       const float* __restrict__ rwk, const float* __restrict__ rwv,
                       const float* __restrict__ rwo, const float* __restrict__ swk,
                       u16* __restrict__ embs_bf, u16* __restrict__ wq_bf,
                       u16* __restrict__ wk_bf, u16* __restrict__ wv_bf,
                       u16* __restrict__ wo_bf, u16* __restrict__ swk_bf,
                       float* __restrict__ nodes) {
  int i = blockIdx.x * 256 + threadIdx.x;
  int which = blockIdx.y;
  if (which == 6) {
    reinterpret_cast<float4*>(nodes)[i] = reinterpret_cast<const float4*>(data)[i];
    return;
  }
  const float* src;
  u16* dst;
  switch (which) {
    case 0: src = data; dst = embs_bf; break;
    case 1: src = rwq; dst = wq_bf; break;
    case 2: src = rwk; dst = wk_bf; break;
    case 3: src = rwv; dst = wv_bf; break;
    case 4: src = rwo; dst = wo_bf; break;
    default: src = swk; dst = swk_bf; break;
  }
  float4 v = reinterpret_cast<const float4*>(src)[i];
  ushort4 o;
  o.x = f2bf(v.x); o.y = f2bf(v.y); o.z = f2bf(v.z); o.w = f2bf(v.w);
  reinterpret_cast<ushort4*>(dst)[i] = o;
}

// ---------- relay init ----------
__global__ void k_relay_part(const float* __restrict__ data, float* __restrict__ part) {
  int b = blockIdx.z, chunk = blockIdx.y;
  int c = blockIdx.x * 256 + threadIdx.x;
  const float* p = data + ((size_t)b * L_ + chunk * 128) * H_ + c;
  float acc = 0.f;
  for (int l = 0; l < 128; ++l) acc += p[(size_t)l * H_];
  part[((size_t)b * 8 + chunk) * H_ + c] = acc;
}
__global__ void k_relay_reduce(const float* __restrict__ part, float* __restrict__ relay) {
  int i = blockIdx.x * 256 + threadIdx.x;
  int b = i >> 10, c = i & 1023;
  float acc = 0.f;
  for (int j = 0; j < 8; ++j) acc += part[((size_t)b * 8 + j) * H_ + c];
  relay[i] = acc * (1.f / (float)L_);
}

// ---------- LayerNorm rows of nodes [B,L,H]; fused pad-row zeroing ----------
// do_zero: zero pad rows of nodes (memory) BEFORE normalizing (== end-of-prev-iter zeroing).
__global__ __launch_bounds__(256) void k_layernorm_bf(float* __restrict__ nodes,
                                                      const float* __restrict__ s,
                                                      const float* __restrict__ bb,
                                                      const int* __restrict__ mask,
                                                      u16* __restrict__ y, int do_zero) {
  int row = blockIdx.x * 4 + (threadIdx.x >> 6);
  int lane = threadIdx.x & 63;
  int b = row >> 10, l = row & 1023;
  bool pad = do_zero && (mask[b * L_ + l] == 0);
  float4* xr = reinterpret_cast<float4*>(nodes + (size_t)row * H_);
  float4 v[4];
  float sum = 0.f, sq = 0.f;
#pragma unroll
  for (int j = 0; j < 4; ++j) {
    v[j] = pad ? float4{0.f, 0.f, 0.f, 0.f} : xr[lane + 64 * j];
    sum += v[j].x + v[j].y + v[j].z + v[j].w;
    sq += v[j].x * v[j].x + v[j].y * v[j].y + v[j].z * v[j].z + v[j].w * v[j].w;
  }
  if (pad) {
#pragma unroll
    for (int j = 0; j < 4; ++j) xr[lane + 64 * j] = float4{0.f, 0.f, 0.f, 0.f};
  }
#pragma unroll
  for (int off = 32; off; off >>= 1) {
    sum += __shfl_xor(sum, off);
    sq += __shfl_xor(sq, off);
  }
  float mu = sum * (1.f / (float)H_);
  float rstd = rsqrtf(sq * (1.f / (float)H_) - mu * mu + 1e-5f);
  ushort4* yr = reinterpret_cast<ushort4*>(y + (size_t)row * H_);
#pragma unroll
  for (int j = 0; j < 4; ++j) {
    int c4 = lane + 64 * j;
    float4 sc = reinterpret_cast<const float4*>(s)[c4];
    float4 bc = reinterpret_cast<const float4*>(bb)[c4];
    ushort4 o;
    o.x = f2bf((v[j].x - mu) * rstd * sc.x + bc.x);
    o.y = f2bf((v[j].y - mu) * rstd * sc.y + bc.y);
    o.z = f2bf((v[j].z - mu) * rstd * sc.z + bc.z);
    o.w = f2bf((v[j].w - mu) * rstd * sc.w + bc.w);
    yr[c4] = o;
  }
}

// ================= 128x128 MFMA GEMM bodies =================
// Common staging: sW[128][32], sX[128][32] bf16, XOR-swizzled k-slots,
// pre-swizzled global source (rule 21). 4 waves: wm=w>>1 (M-half), wn=w&1 (N-half).
// Per K-step: 4 gl_lds16 issues/thread, 8 ds_read_b128, 16 MFMA per wave.

#define GEMM_PROLOGUE(XPTR, WPTR)                                              \
  __shared__ __align__(16) u16 sX[128 * 32];                                   \
  __shared__ __align__(16) u16 sW[128 * 32];                                   \
  const int t = threadIdx.x;                                                   \
  const int w = t >> 6, lane = t & 63;                                         \
  const int wm = w >> 1, wn = w & 1;                                           \
  const int r4 = lane >> 2, slot = lane & 3;                                   \
  const int rowS0 = w * 16 + r4, rowS1 = 64 + rowS0;                           \
  const int colS0 = ((slot ^ ((rowS0 >> 1) & 3)) << 3);                        \
  const int colS1 = ((slot ^ ((rowS1 >> 1) & 3)) << 3);                        \
  const u16* gX0 = (XPTR) + (size_t)(bm + rowS0) * 1024 + colS0;               \
  const u16* gX1 = (XPTR) + (size_t)(bm + rowS1) * 1024 + colS1;               \
  const u16* gW0 = (WPTR) + (size_t)(bn + rowS0) * 1024 + colS0;               \
  const u16* gW1 = (WPTR) + (size_t)(bn + rowS1) * 1024 + colS1;               \
  u16* lX0 = sX + (size_t)w * 512;                                             \
  u16* lX1 = sX + (size_t)(4 + w) * 512;                                       \
  u16* lW0 = sW + (size_t)w * 512;                                             \
  u16* lW1 = sW + (size_t)(4 + w) * 512;                                       \
  const int kidx = (((lane >> 4) ^ ((lane >> 1) & 3)) << 3);                   \
  f32x4 acc[4][4];                                                             \
  _Pragma("unroll") for (int i_ = 0; i_ < 4; ++i_)                             \
      _Pragma("unroll") for (int j_ = 0; j_ < 4; ++j_)                         \
          acc[i_][j_] = f32x4{0.f, 0.f, 0.f, 0.f};

#define GEMM_KLOOP(AROWBASE, BROWBASE, ASRC, BSRC)                             \
  for (int ck = 0; ck < 1024; ck += 32) {                                      \
    gl_lds16(gX0, lX0);                                                        \
    gl_lds16(gX1, lX1);                                                        \
    gl_lds16(gW0, lW0);                                                        \
    gl_lds16(gW1, lW1);                                                        \
    gX0 += 32; gX1 += 32; gW0 += 32; gW1 += 32;                                \
    __syncthreads();                                                           \
    short8 af_[4], bf_[4];                                                     \
    _Pragma("unroll") for (int mf = 0; mf < 4; ++mf)                           \
        af_[mf] = *reinterpret_cast<const short8*>(                            \
            &ASRC[((AROWBASE) + mf * 16) * 32 + kidx]);                        \
    _Pragma("unroll") for (int nf = 0; nf < 4; ++nf)                           \
        bf_[nf] = *reinterpret_cast<const short8*>(                            \
            &BSRC[((BROWBASE) + nf * 16) * 32 + kidx]);                        \
    _Pragma("unroll") for (int mf = 0; mf < 4; ++mf)                           \
        _Pragma("unroll") for (int nf = 0; nf < 4; ++nf)                       \
            acc[mf][nf] = __builtin_amdgcn_mfma_f32_16x16x32_bf16(             \
                af_[mf], bf_[nf], acc[mf][nf], 0, 0, 0);                       \
    __syncthreads();                                                          \
  }

// ---- 5-in-1 GEMM, swapped orientation (A=W -> M=o, B=X -> N=l(B*L)) ----
// which: 0,1,2 = q,k,v from xn; 3,4 = ke,ve from embs. Out bf16 [which][B*L][1024].
__global__ __launch_bounds__(256) void k_gemm5(const u16* __restrict__ wq,
                                               const u16* __restrict__ wk,
                                               const u16* __restrict__ wv,
                                               const float* __restrict__ bq,
                                               const float* __restrict__ bk,
                                               const float* __restrict__ bv,
                                               const u16* __restrict__ xn,
                                               const u16* __restrict__ embs,
                                               u16* __restrict__ Y) {
  const int bm = blockIdx.x * 128;            // bl rows
  const int which = blockIdx.y >> 3;
  const int bn = (blockIdx.y & 7) * 128;      // o
  const u16* W = (which == 0) ? wq : ((which == 1 || which == 3) ? wk : wv);
  const float* bias = (which == 0) ? bq : ((which == 1 || which == 3) ? bk : bv);
  const u16* X = (which < 3) ? xn : embs;
  u16* Yw = Y + (size_t)which * ((size_t)B_ * L_ * ND_);

  GEMM_PROLOGUE(X, W)
  const int rW = wm * 64 + (lane & 15);
  const int rX = wn * 64 + (lane & 15);
  GEMM_KLOOP(rW, rX, sW, sX)

#pragma unroll
  for (int mo = 0; mo < 4; ++mo) {
    int o0 = bn + wm * 64 + mo * 16 + ((lane >> 4) << 2);
    float4 bs = *reinterpret_cast<const float4*>(bias + o0);
#pragma unroll
    for (int nl = 0; nl < 4; ++nl) {
      int bl = bm + wn * 64 + nl * 16 + (lane & 15);
      f32x4 vv = acc[mo][nl];
      ushort4 ov;
      ov.x = f2bf(vv[0] + bs.x);
      ov.y = f2bf(vv[1] + bs.y);
      ov.z = f2bf(vv[2] + bs.z);
      ov.w = f2bf(vv[3] + bs.w);
      *reinterpret_cast<ushort4*>(&Yw[(size_t)bl * 1024 + o0]) = ov;
    }
  }
}

// ---- Wo GEMM, swapped orientation; nodes[B*L,H] += leaky(val); nodes_bf = bf16 ----
__global__ __launch_bounds__(256) void k_gemm_wo(const u16* __restrict__ W,
                                                 const float* __restrict__ bias,
                                                 const u16* __restrict__ X,
                                                 float* __restrict__ nodes,
                                                 u16* __restrict__ nodes_bf) {
  const int bm = blockIdx.x * 128;  // bl
  const int bn = blockIdx.y * 128;  // o
  GEMM_PROLOGUE(X, W)
  const int rW = wm * 64 + (lane & 15);
  const int rX = wn * 64 + (lane & 15);
  GEMM_KLOOP(rW, rX, sW, sX)

#pragma unroll
  for (int mo = 0; mo < 4; ++mo) {
    int o0 = bn + wm * 64 + mo * 16 + ((lane >> 4) << 2);
    float4 bs = *reinterpret_cast<const float4*>(bias + o0);
#pragma unroll
    for (int nl = 0; nl < 4; ++nl) {
      int bl = bm + wn * 64 + nl * 16 + (lane & 15);
      size_t ni = (size_t)bl * 1024 + o0;
      float4 cur = *reinterpret_cast<const float4*>(&nodes[ni]);
      f32x4 vv = acc[mo][nl];
      float r0 = vv[0] + bs.x; r0 = cur.x + (r0 > 0.f ? r0 : 0.01f * r0);
      float r1 = vv[1] + bs.y; r1 = cur.y + (r1 > 0.f ? r1 : 0.01f * r1);
      float r2 = vv[2] + bs.z; r2 = cur.z + (r2 > 0.f ? r2 : 0.01f * r2);
      float r3 = vv[3] + bs.w; r3 = cur.w + (r3 > 0.f ? r3 : 0.01f * r3);
      *reinterpret_cast<float4*>(&nodes[ni]) = float4{r0, r1, r2, r3};
      ushort4 ov;
      ov.x = f2bf(r0); ov.y = f2bf(r1); ov.z = f2bf(r2); ov.w = f2bf(r3);
      *reinterpret_cast<ushort4*>(&nodes_bf[ni]) = ov;
    }
  }
}

// ---- kkb GEMM, original orientation (A=X -> M=l, B=W -> N=o); out fp32 [b][o][1+l] ----
__global__ __launch_bounds__(256) void k_gemm_kkb(const u16* __restrict__ W,
                                                  const float* __restrict__ bias,
                                                  const u16* __restrict__ X,
                                                  float* __restrict__ Y) {
  const int bm = blockIdx.x * 128;  // bl
  const int bn = blockIdx.y * 128;  // o
  GEMM_PROLOGUE(X, W)
  const int rX = wm * 64 + (lane & 15);
  const int rW = wn * 64 + (lane & 15);
  GEMM_KLOOP(rX, rW, sX, sW)

#pragma unroll
  for (int nf = 0; nf < 4; ++nf) {
    int o = bn + wn * 64 + nf * 16 + (lane & 15);
    float bs = bias[o];
#pragma unroll
    for (int mf = 0; mf < 4; ++mf) {
      int gl = bm + wm * 64 + mf * 16 + ((lane >> 4) << 2);
      int b = gl >> 10, l = gl & 1023;
      size_t yi = ((size_t)(b * 1024 + o)) * (size_t)(L_ + 1) + 1 + l;
      f32x4 v = acc[mf][nf];
#pragma unroll
      for (int r = 0; r < 4; ++r) Y[yi + r] = v[r] + bs;
    }
  }
}

// ---------- dual matvec: wave per output; z selects set ----------
__global__ __launch_bounds__(256) void k_matvec2(const float* __restrict__ W0,
                                                 const float* __restrict__ b0,
                                                 float* __restrict__ y0, long sB0, long sO0,
                                                 const float* __restrict__ W1,
                                                 const float* __restrict__ b1,
                                                 float* __restrict__ y1, long sB1, long sO1,
                                                 const float* __restrict__ x) {
  int b = blockIdx.y;
  int z = blockIdx.z;
  const float* W = z ? W1 : W0;
  const float* bias = z ? b1 : b0;
  float* y = z ? y1 : y0;
  long sB = z ? sB1 : sB0, sO = z ? sO1 : sO0;
  int o = blockIdx.x * 4 + (threadIdx.x >> 6);
  int lane = threadIdx.x & 63;
  const float* wr = W + (size_t)o * 1024;
  const float* xb = x + (size_t)b * 1024;
  float acc = 0.f;
  for (int c = lane; c < 1024; c += 64) acc += wr[c] * xb[c];
#pragma unroll
  for (int off = 32; off; off >>= 1) acc += __shfl_xor(acc, off);
  if (lane == 0) y[(size_t)b * sB + (size_t)o * sO] = acc + bias[o];
}

// ---------- single matvec (relay update, leaky) ----------
__global__ __launch_bounds__(256) void k_matvec(const float* __restrict__ W,
                                                const float* __restrict__ bias,
                                                const float* __restrict__ x,
                                                float* __restrict__ y) {
  int b = blockIdx.y;
  int o = blockIdx.x * 4 + (threadIdx.x >> 6);
  int lane = threadIdx.x & 63;
  const float* wr = W + (size_t)o * 1024;
  const float* xb = x + (size_t)b * 1024;
  float acc = 0.f;
  for (int c = lane; c < 1024; c += 64) acc += wr[c] * xb[c];
#pragma unroll
  for (int off = 32; off; off >>= 1) acc += __shfl_xor(acc, off);
  if (lane == 0) {
    acc += bias[o];
    y[(size_t)b * 1024 + o] = acc > 0.f ? acc : 0.01f * acc;
  }
}

// ---------- msa1 ring attention, bf16 [B,L,ND] inputs ----------
__global__ __launch_bounds__(256) void k_msa1(const u16* __restrict__ q,
                                              const u16* __restrict__ k,
                                              const u16* __restrict__ v,
                                              const u16* __restrict__ ke,
                                              const u16* __restrict__ ve,
                                              const float* __restrict__ rk,
                                              const float* __restrict__ rv,
                                              u16* __restrict__ attbf) {
  int t = threadIdx.x;
  int head = t & 15, dh = (t >> 4) & 1, lsub = t >> 5;
  int l = blockIdx.x * 8 + lsub;
  int b = blockIdx.z;
  size_t row = ((size_t)(b * 1024 + l)) * 1024 + head * 64 + dh * 32;
  size_t rbase = (size_t)b * 1024 + head * 64 + dh * 32;

  float qf[32];
  {
    const short8* qp = reinterpret_cast<const short8*>(q + row);
#pragma unroll
    for (int j = 0; j < 4; ++j) {
      short8 qv = qp[j];
#pragma unroll
      for (int e = 0; e < 8; ++e) qf[j * 8 + e] = bf2f((u16)qv[e]);
    }
  }
  float s[7];
#pragma unroll
  for (int u = 0; u < 5; ++u) {
    int lk = l + u - 2;
    float su = 0.f;
    if (lk >= 0 && lk < L_) {
      const short8* kp =
          reinterpret_cast<const short8*>(k + ((size_t)(b * 1024 + lk)) * 1024 + head * 64 + dh * 32);
#pragma unroll
      for (int j = 0; j < 4; ++j) {
        short8 kv = kp[j];
#pragma unroll
        for (int e = 0; e < 8; ++e) su = fmaf(qf[j * 8 + e], bf2f((u16)kv[e]), su);
      }
    }
    s[u] = su;
  }
  {
    float su = 0.f;
    const short8* kp = reinterpret_cast<const short8*>(ke + row);
#pragma unroll
    for (int j = 0; j < 4; ++j) {
      short8 kv = kp[j];
#pragma unroll
      for (int e = 0; e < 8; ++e) su = fmaf(qf[j * 8 + e], bf2f((u16)kv[e]), su);
    }
    s[5] = su;
  }
  {
    float su = 0.f;
    const float4* rp = reinterpret_cast<const float4*>(rk + rbase);
#pragma unroll
    for (int j = 0; j < 8; ++j) {
      float4 r4 = rp[j];
      su = fmaf(qf[j * 4 + 0], r4.x, su);
      su = fmaf(qf[j * 4 + 1], r4.y, su);
      su = fmaf(qf[j * 4 + 2], r4.z, su);
      su = fmaf(qf[j * 4 + 3], r4.w, su);
    }
    s[6] = su;
  }
#pragma unroll
  for (int u = 0; u < 7; ++u) s[u] += __shfl_xor(s[u], 16);
  float m = -1e30f;
#pragma unroll
  for (int u = 0; u < 7; ++u) {
    s[u] *= 0.125f;
    m = fmaxf(m, s[u]);
  }
  float e[7], tot = 0.f;
#pragma unroll
  for (int u = 0; u < 7; ++u) {
    e[u] = expf(s[u] - m);
    tot += e[u];
  }
  float inv = 1.f / tot;
#pragma unroll
  for (int u = 0; u < 7; ++u) e[u] *= inv;

  float av[32];
  {
    const float4* rp = reinterpret_cast<const float4*>(rv + rbase);
#pragma unroll
    for (int j = 0; j < 8; ++j) {
      float4 r4 = rp[j];
      av[j * 4 + 0] = e[6] * r4.x;
      av[j * 4 + 1] = e[6] * r4.y;
      av[j * 4 + 2] = e[6] * r4.z;
      av[j * 4 + 3] = e[6] * r4.w;
    }
  }
  {
    const short8* vp = reinterpret_cast<const short8*>(ve + row);
#pragma unroll
    for (int j = 0; j < 4; ++j) {
      short8 vv = vp[j];
#pragma unroll
      for (int ee = 0; ee < 8; ++ee) av[j * 8 + ee] = fmaf(e[5], bf2f((u16)vv[ee]), av[j * 8 + ee]);
    }
  }
#pragma unroll
  for (int u = 0; u < 5; ++u) {
    int lk = l + u - 2;
    if (lk >= 0 && lk < L_) {
      const short8* vp =
          reinterpret_cast<const short8*>(v + ((size_t)(b * 1024 + lk)) * 1024 + head * 64 + dh * 32);
#pragma unroll
      for (int j = 0; j < 4; ++j) {
        short8 vv = vp[j];
#pragma unroll
        for (int ee = 0; ee < 8; ++ee) av[j * 8 + ee] = fmaf(e[u], bf2f((u16)vv[ee]), av[j * 8 + ee]);
      }
    }
  }
  u16 ob[32];
#pragma unroll
  for (int j = 0; j < 32; ++j) ob[j] = f2bf(av[j]);
  uint4* d4 = reinterpret_cast<uint4*>(attbf + row);
  const uint4* s4 = reinterpret_cast<const uint4*>(ob);
#pragma unroll
  for (int j = 0; j < 4; ++j) d4[j] = s4[j];
}

// ---------- msa2 star attention (v = k, faithful) ----------
__global__ __launch_bounds__(1024) void k_msa2(const float* __restrict__ rq,
                                               const float* __restrict__ kk,
                                               const int* __restrict__ mask,
                                               float* __restrict__ satt) {
  int n = blockIdx.x, b = blockIdx.y;
  int t = threadIdx.x;
  __shared__ float sq_[HD_];
  __shared__ float se[L_ + 1];
  __shared__ float swsum[16];
  __shared__ float stot;
  size_t rb = (size_t)(b * NH_ + n) * HD_;
  if (t < HD_) sq_[t] = rq[rb + t];
  __syncthreads();
  const float* kb = kk + rb * (size_t)(L_ + 1);
  float ls = 0.f;
  for (int p = t; p < L_ + 1; p += 1024) {
    float e;
    if (p > 0 && mask[b * L_ + p - 1] == 0) {
      e = 0.f;
    } else {
      float acc = 0.f;
      for (int d = 0; d < HD_; ++d) acc = fmaf(sq_[d], kb[(size_t)d * (L_ + 1) + p], acc);
      e = expf(acc * 0.125f);
    }
    se[p] = e;
    ls += e;
  }
  int lane = t & 63, w = t >> 6;
#pragma unroll
  for (int off = 32; off; off >>= 1) ls += __shfl_xor(ls, off);
  if (lane == 0) swsum[w] = ls;
  __syncthreads();
  if (t == 0) {
    float tot = 0.f;
    for (int j = 0; j < 16; ++j) tot += swsum[j];
    stot = 1.f / tot;
  }
  __syncthreads();
  float inv = stot;
  float acc[4] = {0.f, 0.f, 0.f, 0.f};
  const float* kw = kb + (size_t)(w * 4) * (L_ + 1);
  for (int p = lane; p < L_ + 1; p += 64) {
    float e = se[p];
#pragma unroll
    for (int j = 0; j < 4; ++j) acc[j] = fmaf(e, kw[(size_t)j * (L_ + 1) + p], acc[j]);
  }
#pragma unroll
  for (int j = 0; j < 4; ++j) {
    float a = acc[j];
#pragma unroll
    for (int off = 32; off; off >>= 1) a += __shfl_xor(a, off);
    if (lane == 0) satt[rb + w * 4 + j] = a * inv;
  }
}

// ---------- final: out = pad ? 0 : nodes (fused last-iter zeroing) ----------
__global__ void k_final(const float* __restrict__ nodes, const int* __restrict__ mask,
                        float* __restrict__ out) {
  int i = blockIdx.x * 256 + threadIdx.x;
  int row = i >> 8;
  int b = row >> 10, l = row & 1023;
  float4 v = (mask[b * L_ + l] == 0) ? float4{0.f, 0.f, 0.f, 0.f}
                                     : reinterpret_cast<const float4*>(nodes)[i];
  reinterpret_cast<float4*>(out)[i] = v;
}

__global__ void k_copy_relay(const float* __restrict__ relay, float* __restrict__ out) {
  int i = blockIdx.x * 256 + threadIdx.x;
  out[i] = relay[i];
}

}  // namespace

extern "C" void kernel_launch(void* const* d_in, const int* in_sizes, int n_in,
                              void* d_out, int out_size, void* d_ws, size_t ws_size,
                              hipStream_t stream) {
  (void)in_sizes; (void)n_in; (void)out_size; (void)ws_size;
  const float* data = (const float*)d_in[0];
  const int* mask = (const int*)d_in[1];
  const float* ln_s = (const float*)d_in[2];
  const float* ln_b = (const float*)d_in[3];
  const float* rwq = (const float*)d_in[4];
  const float* rwq_b = (const float*)d_in[5];
  const float* rwk = (const float*)d_in[6];
  const float* rwk_b = (const float*)d_in[7];
  const float* rwv = (const float*)d_in[8];
  const float* rwv_b = (const float*)d_in[9];
  const float* rwo = (const float*)d_in[10];
  const float* rwo_b = (const float*)d_in[11];
  const float* swq = (const float*)d_in[12];
  const float* swq_b = (const float*)d_in[13];
  const float* swk = (const float*)d_in[14];
  const float* swk_b = (const float*)d_in[15];
  const float* swo = (const float*)d_in[16];
  const float* swo_b = (const float*)d_in[17];
  float* out = (float*)d_out;

  const size_t SZ = (size_t)B_ * ND_ * L_;  // 4M elements
  float* f = (float*)d_ws;
  float* nodes = f; f += SZ;                       // fp32 [B,L,H]
  float* kkb = f; f += (size_t)B_ * ND_ * (L_ + 1);
  float* part = f; f += (size_t)B_ * 8 * H_;
  float* relay = f; f += B_ * H_;
  float* rk = f; f += B_ * ND_;
  float* rv = f; f += B_ * ND_;
  float* rq = f; f += B_ * ND_;
  float* satt = f; f += B_ * ND_;
  u16* u = (u16*)f;
  u16* xn_bf = u; u += SZ;       // [B,L,H]
  u16* embs_bf = u; u += SZ;     // [B,L,H]
  u16* att_bf = u; u += SZ;      // [B,L,ND]
  u16* nodes_bf = u; u += SZ;    // [B,L,H]
  u16* qkv5_bf = u; u += 5 * SZ; // [5][B,L,ND]: q,k,v,ke,ve
  u16* wq_bf = u; u += SZ;
  u16* wk_bf = u; u += SZ;
  u16* wv_bf = u; u += SZ;
  u16* wo_bf = u; u += SZ;
  u16* swk_bf = u; u += SZ;

  k_prep<<<dim3(4096, 7), 256, 0, stream>>>(data, rwq, rwk, rwv, rwo, swk,
                                            embs_bf, wq_bf, wk_bf, wv_bf, wo_bf, swk_bf, nodes);
  k_relay_part<<<dim3(H_ / 256, 8, B_), 256, 0, stream>>>(data, part);
  k_relay_reduce<<<dim3((B_ * H_) / 256), 256, 0, stream>>>(part, relay);

  for (int i = 0; i < ITERS_; ++i) {
    const u16* wq_i = wq_bf + (size_t)i * ND_ * H_;
    const u16* wk_i = wk_bf + (size_t)i * ND_ * H_;
    const u16* wv_i = wv_bf + (size_t)i * ND_ * H_;
    const u16* wo_i = wo_bf + (size_t)i * H_ * ND_;
    const u16* sk_i = swk_bf + (size_t)i * ND_ * H_;

    k_layernorm_bf<<<dim3(B_ * L_ / 4), 256, 0, stream>>>(nodes, ln_s + i * H_, ln_b + i * H_,
                                                          mask, xn_bf, i > 0 ? 1 : 0);
    // q,k,v,ke,ve in one dispatch (M=o 128, N=bl 128, 5*8 o-tiles)
    k_gemm5<<<dim3(32, 40), 256, 0, stream>>>(wq_i, wk_i, wv_i,
                                              rwq_b + i * ND_, rwk_b + i * ND_, rwv_b + i * ND_,
                                              xn_bf, embs_bf, qkv5_bf);
    // rk, rv (fp32 weights)
    k_matvec2<<<dim3(256, B_, 2), 256, 0, stream>>>(
        rwk + (size_t)i * ND_ * H_, rwk_b + i * ND_, rk, ND_, 1,
        rwv + (size_t)i * ND_ * H_, rwv_b + i * ND_, rv, ND_, 1, relay);
    k_msa1<<<dim3(L_ / 8, 1, B_), 256, 0, stream>>>(qkv5_bf, qkv5_bf + SZ, qkv5_bf + 2 * SZ,
                                                    qkv5_bf + 3 * SZ, qkv5_bf + 4 * SZ, rk, rv, att_bf);
    k_gemm_wo<<<dim3(32, 8), 256, 0, stream>>>(wo_i, rwo_b + i * H_, att_bf, nodes, nodes_bf);
    // rq and kkb col0 (old relay)
    k_matvec2<<<dim3(256, B_, 2), 256, 0, stream>>>(
        swq + (size_t)i * ND_ * H_, swq_b + i * ND_, rq, ND_, 1,
        swk + (size_t)i * ND_ * H_, swk_b + i * ND_, kkb, (long)ND_ * (L_ + 1), L_ + 1, relay);
    k_gemm_kkb<<<dim3(32, 8), 256, 0, stream>>>(sk_i, swk_b + i * ND_, nodes_bf, kkb);
    k_msa2<<<dim3(NH_, B_), 1024, 0, stream>>>(rq, kkb, mask, satt);
    k_matvec<<<dim3(256, B_), 256, 0, stream>>>(swo + (size_t)i * H_ * ND_, swo_b + i * H_, satt, relay);
  }
  k_final<<<4096, 256, 0, stream>>>(nodes, mask, out);
  k_copy_relay<<<dim3((B_ * H_) / 256), 256, 0, stream>>>(relay, out + (size_t)B_ * L_ * H_);
}

// Round 7
// 764.221 us; speedup vs baseline: 6.8127x; 1.0047x over previous
//
#include <hip/hip_runtime.h>
#include <math.h>

namespace {

constexpr int B_ = 4, L_ = 1024, H_ = 1024, NH_ = 16, HD_ = 64, ND_ = 1024, ITERS_ = 4;

typedef unsigned short u16;
typedef __attribute__((ext_vector_type(8))) short short8;
typedef __attribute__((ext_vector_type(4))) float f32x4;

__device__ inline u16 f2bf(float f) {
  unsigned u = __builtin_bit_cast(unsigned, f);
  u += 0x7FFFu + ((u >> 16) & 1u);
  return (u16)(u >> 16);
}
__device__ inline float bf2f(u16 v) {
  unsigned u = ((unsigned)v) << 16;
  return __builtin_bit_cast(float, u);
}

__device__ inline void gl_lds16(const u16* g, u16* l) {
  __builtin_amdgcn_global_load_lds((const __attribute__((address_space(1))) void*)g,
                                   (__attribute__((address_space(3))) void*)l, 16, 0, 0);
}

// ---------- prep: 6 f2bf conversions + nodes copy, one dispatch ----------
__global__ void k_prep(const float* __restrict__ data, const float* __restrict__ rwq,
                       const float* __restrict__ rwk, const float* __restrict__ rwv,
                       const float* __restrict__ rwo, const float* __restrict__ swk,
                       u16* __restrict__ embs_bf, u16* __restrict__ wq_bf,
                       u16* __restrict__ wk_bf, u16* __restrict__ wv_bf,
                       u16* __restrict__ wo_bf, u16* __restrict__ swk_bf,
                       float* __restrict__ nodes) {
  int i = blockIdx.x * 256 + threadIdx.x;
  int which = blockIdx.y;
  if (which == 6) {
    reinterpret_cast<float4*>(nodes)[i] = reinterpret_cast<const float4*>(data)[i];
    return;
  }
  const float* src;
  u16* dst;
  switch (which) {
    case 0: src = data; dst = embs_bf; break;
    case 1: src = rwq; dst = wq_bf; break;
    case 2: src = rwk; dst = wk_bf; break;
    case 3: src = rwv; dst = wv_bf; break;
    case 4: src = rwo; dst = wo_bf; break;
    default: src = swk; dst = swk_bf; break;
  }
  float4 v = reinterpret_cast<const float4*>(src)[i];
  ushort4 o;
  o.x = f2bf(v.x); o.y = f2bf(v.y); o.z = f2bf(v.z); o.w = f2bf(v.w);
  reinterpret_cast<ushort4*>(dst)[i] = o;
}

// ---------- relay init ----------
__global__ void k_relay_part(const float* __restrict__ data, float* __restrict__ part) {
  int b = blockIdx.z, chunk = blockIdx.y;
  int c = blockIdx.x * 256 + threadIdx.x;
  const float* p = data + ((size_t)b * L_ + chunk * 128) * H_ + c;
  float acc = 0.f;
  for (int l = 0; l < 128; ++l) acc += p[(size_t)l * H_];
  part[((size_t)b * 8 + chunk) * H_ + c] = acc;
}
__global__ void k_relay_reduce(const float* __restrict__ part, float* __restrict__ relay) {
  int i = blockIdx.x * 256 + threadIdx.x;
  int b = i >> 10, c = i & 1023;
  float acc = 0.f;
  for (int j = 0; j < 8; ++j) acc += part[((size_t)b * 8 + j) * H_ + c];
  relay[i] = acc * (1.f / (float)L_);
}

// ---------- LayerNorm rows of nodes [B,L,H]; fused pad-row zeroing ----------
__global__ __launch_bounds__(256) void k_layernorm_bf(float* __restrict__ nodes,
                                                      const float* __restrict__ s,
                                                      const float* __restrict__ bb,
                                                      const int* __restrict__ mask,
                                                      u16* __restrict__ y, int do_zero) {
  int row = blockIdx.x * 4 + (threadIdx.x >> 6);
  int lane = threadIdx.x & 63;
  int b = row >> 10, l = row & 1023;
  bool pad = do_zero && (mask[b * L_ + l] == 0);
  float4* xr = reinterpret_cast<float4*>(nodes + (size_t)row * H_);
  float4 v[4];
  float sum = 0.f, sq = 0.f;
#pragma unroll
  for (int j = 0; j < 4; ++j) {
    v[j] = pad ? float4{0.f, 0.f, 0.f, 0.f} : xr[lane + 64 * j];
    sum += v[j].x + v[j].y + v[j].z + v[j].w;
    sq += v[j].x * v[j].x + v[j].y * v[j].y + v[j].z * v[j].z + v[j].w * v[j].w;
  }
  if (pad) {
#pragma unroll
    for (int j = 0; j < 4; ++j) xr[lane + 64 * j] = float4{0.f, 0.f, 0.f, 0.f};
  }
#pragma unroll
  for (int off = 32; off; off >>= 1) {
    sum += __shfl_xor(sum, off);
    sq += __shfl_xor(sq, off);
  }
  float mu = sum * (1.f / (float)H_);
  float rstd = rsqrtf(sq * (1.f / (float)H_) - mu * mu + 1e-5f);
  ushort4* yr = reinterpret_cast<ushort4*>(y + (size_t)row * H_);
#pragma unroll
  for (int j = 0; j < 4; ++j) {
    int c4 = lane + 64 * j;
    float4 sc = reinterpret_cast<const float4*>(s)[c4];
    float4 bc = reinterpret_cast<const float4*>(bb)[c4];
    ushort4 o;
    o.x = f2bf((v[j].x - mu) * rstd * sc.x + bc.x);
    o.y = f2bf((v[j].y - mu) * rstd * sc.y + bc.y);
    o.z = f2bf((v[j].z - mu) * rstd * sc.z + bc.z);
    o.w = f2bf((v[j].w - mu) * rstd * sc.w + bc.w);
    yr[c4] = o;
  }
}

// ================= 128x128 MFMA GEMM bodies (double-buffered 2-phase) =================
// LDS: 2 x (sX 8KB + sW 8KB) = 32KB. Stage tile t+1 into buf^1 BEFORE computing
// tile t; counted s_waitcnt vmcnt(4) keeps the 4 next-tile loads in flight across
// the barrier (T3 minimum 2-phase; never drain to 0 in main loop).

#define GEMM_PROLOGUE(XPTR, WPTR)                                              \
  __shared__ __align__(16) u16 sX[2][128 * 32];                                \
  __shared__ __align__(16) u16 sW[2][128 * 32];                                \
  const int t = threadIdx.x;                                                   \
  const int w = t >> 6, lane = t & 63;                                         \
  const int wm = w >> 1, wn = w & 1;                                           \
  const int r4 = lane >> 2, slot = lane & 3;                                   \
  const int rowS0 = w * 16 + r4, rowS1 = 64 + rowS0;                           \
  const int colS0 = ((slot ^ ((rowS0 >> 1) & 3)) << 3);                        \
  const int colS1 = ((slot ^ ((rowS1 >> 1) & 3)) << 3);                        \
  const u16* gX0 = (XPTR) + (size_t)(bm + rowS0) * 1024 + colS0;               \
  const u16* gX1 = (XPTR) + (size_t)(bm + rowS1) * 1024 + colS1;               \
  const u16* gW0 = (WPTR) + (size_t)(bn + rowS0) * 1024 + colS0;               \
  const u16* gW1 = (WPTR) + (size_t)(bn + rowS1) * 1024 + colS1;               \
  const int kidx = (((lane >> 4) ^ ((lane >> 1) & 3)) << 3);                   \
  f32x4 acc[4][4];                                                             \
  _Pragma("unroll") for (int i_ = 0; i_ < 4; ++i_)                             \
      _Pragma("unroll") for (int j_ = 0; j_ < 4; ++j_)                         \
          acc[i_][j_] = f32x4{0.f, 0.f, 0.f, 0.f};

#define GEMM_STAGE(BUF)                                                        \
  gl_lds16(gX0, sX[BUF] + w * 512);                                            \
  gl_lds16(gX1, sX[BUF] + (4 + w) * 512);                                      \
  gl_lds16(gW0, sW[BUF] + w * 512);                                            \
  gl_lds16(gW1, sW[BUF] + (4 + w) * 512);                                      \
  gX0 += 32; gX1 += 32; gW0 += 32; gW1 += 32;

#define GEMM_KLOOP_DB(AROWBASE, BROWBASE, ASRC, BSRC)                          \
  int cur = 0;                                                                 \
  GEMM_STAGE(0)                                                                \
  for (int ck = 0; ck < 1024; ck += 32) {                                      \
    if (ck < 992) {                                                            \
      GEMM_STAGE(cur ^ 1)                                                      \
      asm volatile("s_waitcnt vmcnt(4)" ::: "memory");                         \
    } else {                                                                   \
      asm volatile("s_waitcnt vmcnt(0)" ::: "memory");                         \
    }                                                                          \
    __builtin_amdgcn_s_barrier();                                              \
    __builtin_amdgcn_sched_barrier(0);                                         \
    short8 af_[4], bf_[4];                                                     \
    _Pragma("unroll") for (int mf = 0; mf < 4; ++mf)                           \
        af_[mf] = *reinterpret_cast<const short8*>(                            \
            &ASRC[cur][((AROWBASE) + mf * 16) * 32 + kidx]);                   \
    _Pragma("unroll") for (int nf = 0; nf < 4; ++nf)                           \
        bf_[nf] = *reinterpret_cast<const short8*>(                            \
            &BSRC[cur][((BROWBASE) + nf * 16) * 32 + kidx]);                   \
    _Pragma("unroll") for (int mf = 0; mf < 4; ++mf)                           \
        _Pragma("unroll") for (int nf = 0; nf < 4; ++nf)                       \
            acc[mf][nf] = __builtin_amdgcn_mfma_f32_16x16x32_bf16(             \
                af_[mf], bf_[nf], acc[mf][nf], 0, 0, 0);                       \
    __builtin_amdgcn_sched_barrier(0);                                         \
    __builtin_amdgcn_s_barrier();                                              \
    cur ^= 1;                                                                  \
  }

// ---- 5-in-1 GEMM, swapped orientation (A=W -> M=o, B=X -> N=l(B*L)) ----
__global__ __launch_bounds__(256) void k_gemm5(const u16* __restrict__ wq,
                                               const u16* __restrict__ wk,
                                               const u16* __restrict__ wv,
                                               const float* __restrict__ bq,
                                               const float* __restrict__ bk,
                                               const float* __restrict__ bv,
                                               const u16* __restrict__ xn,
                                               const u16* __restrict__ embs,
                                               u16* __restrict__ Y) {
  const int bm = blockIdx.x * 128;            // bl rows
  const int which = blockIdx.y >> 3;
  const int bn = (blockIdx.y & 7) * 128;      // o
  const u16* W = (which == 0) ? wq : ((which == 1 || which == 3) ? wk : wv);
  const float* bias = (which == 0) ? bq : ((which == 1 || which == 3) ? bk : bv);
  const u16* X = (which < 3) ? xn : embs;
  u16* Yw = Y + (size_t)which * ((size_t)B_ * L_ * ND_);

  GEMM_PROLOGUE(X, W)
  const int rW = wm * 64 + (lane & 15);
  const int rX = wn * 64 + (lane & 15);
  GEMM_KLOOP_DB(rW, rX, sW, sX)

#pragma unroll
  for (int mo = 0; mo < 4; ++mo) {
    int o0 = bn + wm * 64 + mo * 16 + ((lane >> 4) << 2);
    float4 bs = *reinterpret_cast<const float4*>(bias + o0);
#pragma unroll
    for (int nl = 0; nl < 4; ++nl) {
      int bl = bm + wn * 64 + nl * 16 + (lane & 15);
      f32x4 vv = acc[mo][nl];
      ushort4 ov;
      ov.x = f2bf(vv[0] + bs.x);
      ov.y = f2bf(vv[1] + bs.y);
      ov.z = f2bf(vv[2] + bs.z);
      ov.w = f2bf(vv[3] + bs.w);
      *reinterpret_cast<ushort4*>(&Yw[(size_t)bl * 1024 + o0]) = ov;
    }
  }
}

// ---- Wo GEMM, swapped orientation; nodes[B*L,H] += leaky(val); nodes_bf = bf16 ----
__global__ __launch_bounds__(256) void k_gemm_wo(const u16* __restrict__ W,
                                                 const float* __restrict__ bias,
                                                 const u16* __restrict__ X,
                                                 float* __restrict__ nodes,
                                                 u16* __restrict__ nodes_bf) {
  const int bm = blockIdx.x * 128;  // bl
  const int bn = blockIdx.y * 128;  // o
  GEMM_PROLOGUE(X, W)
  const int rW = wm * 64 + (lane & 15);
  const int rX = wn * 64 + (lane & 15);
  GEMM_KLOOP_DB(rW, rX, sW, sX)

#pragma unroll
  for (int mo = 0; mo < 4; ++mo) {
    int o0 = bn + wm * 64 + mo * 16 + ((lane >> 4) << 2);
    float4 bs = *reinterpret_cast<const float4*>(bias + o0);
#pragma unroll
    for (int nl = 0; nl < 4; ++nl) {
      int bl = bm + wn * 64 + nl * 16 + (lane & 15);
      size_t ni = (size_t)bl * 1024 + o0;
      float4 curv = *reinterpret_cast<const float4*>(&nodes[ni]);
      f32x4 vv = acc[mo][nl];
      float r0 = vv[0] + bs.x; r0 = curv.x + (r0 > 0.f ? r0 : 0.01f * r0);
      float r1 = vv[1] + bs.y; r1 = curv.y + (r1 > 0.f ? r1 : 0.01f * r1);
      float r2 = vv[2] + bs.z; r2 = curv.z + (r2 > 0.f ? r2 : 0.01f * r2);
      float r3 = vv[3] + bs.w; r3 = curv.w + (r3 > 0.f ? r3 : 0.01f * r3);
      *reinterpret_cast<float4*>(&nodes[ni]) = float4{r0, r1, r2, r3};
      ushort4 ov;
      ov.x = f2bf(r0); ov.y = f2bf(r1); ov.z = f2bf(r2); ov.w = f2bf(r3);
      *reinterpret_cast<ushort4*>(&nodes_bf[ni]) = ov;
    }
  }
}

// ---- kkb GEMM, original orientation (A=X -> M=l, B=W -> N=o); out fp32 [b][o][1+l] ----
__global__ __launch_bounds__(256) void k_gemm_kkb(const u16* __restrict__ W,
                                                  const float* __restrict__ bias,
                                                  const u16* __restrict__ X,
                                                  float* __restrict__ Y) {
  const int bm = blockIdx.x * 128;  // bl
  const int bn = blockIdx.y * 128;  // o
  GEMM_PROLOGUE(X, W)
  const int rX = wm * 64 + (lane & 15);
  const int rW = wn * 64 + (lane & 15);
  GEMM_KLOOP_DB(rX, rW, sX, sW)

#pragma unroll
  for (int nf = 0; nf < 4; ++nf) {
    int o = bn + wn * 64 + nf * 16 + (lane & 15);
    float bs = bias[o];
#pragma unroll
    for (int mf = 0; mf < 4; ++mf) {
      int gl = bm + wm * 64 + mf * 16 + ((lane >> 4) << 2);
      int b = gl >> 10, l = gl & 1023;
      size_t yi = ((size_t)(b * 1024 + o)) * (size_t)(L_ + 1) + 1 + l;
      f32x4 v = acc[mf][nf];
#pragma unroll
      for (int r = 0; r < 4; ++r) Y[yi + r] = v[r] + bs;
    }
  }
}

// ---------- dual matvec: wave per output; z selects set ----------
__global__ __launch_bounds__(256) void k_matvec2(const float* __restrict__ W0,
                                                 const float* __restrict__ b0,
                                                 float* __restrict__ y0, long sB0, long sO0,
                                                 const float* __restrict__ W1,
                                                 const float* __restrict__ b1,
                                                 float* __restrict__ y1, long sB1, long sO1,
                                                 const float* __restrict__ x) {
  int b = blockIdx.y;
  int z = blockIdx.z;
  const float* W = z ? W1 : W0;
  const float* bias = z ? b1 : b0;
  float* y = z ? y1 : y0;
  long sB = z ? sB1 : sB0, sO = z ? sO1 : sO0;
  int o = blockIdx.x * 4 + (threadIdx.x >> 6);
  int lane = threadIdx.x & 63;
  const float* wr = W + (size_t)o * 1024;
  const float* xb = x + (size_t)b * 1024;
  float acc = 0.f;
  for (int c = lane; c < 1024; c += 64) acc += wr[c] * xb[c];
#pragma unroll
  for (int off = 32; off; off >>= 1) acc += __shfl_xor(acc, off);
  if (lane == 0) y[(size_t)b * sB + (size_t)o * sO] = acc + bias[o];
}

// ---------- single matvec (relay update, leaky) ----------
__global__ __launch_bounds__(256) void k_matvec(const float* __restrict__ W,
                                                const float* __restrict__ bias,
                                                const float* __restrict__ x,
                                                float* __restrict__ y) {
  int b = blockIdx.y;
  int o = blockIdx.x * 4 + (threadIdx.x >> 6);
  int lane = threadIdx.x & 63;
  const float* wr = W + (size_t)o * 1024;
  const float* xb = x + (size_t)b * 1024;
  float acc = 0.f;
  for (int c = lane; c < 1024; c += 64) acc += wr[c] * xb[c];
#pragma unroll
  for (int off = 32; off; off >>= 1) acc += __shfl_xor(acc, off);
  if (lane == 0) {
    acc += bias[o];
    y[(size_t)b * 1024 + o] = acc > 0.f ? acc : 0.01f * acc;
  }
}

// ---------- msa1 ring attention, bf16 [B,L,ND] inputs ----------
__global__ __launch_bounds__(256) void k_msa1(const u16* __restrict__ q,
                                              const u16* __restrict__ k,
                                              const u16* __restrict__ v,
                                              const u16* __restrict__ ke,
                                              const u16* __restrict__ ve,
                                              const float* __restrict__ rk,
                                              const float* __restrict__ rv,
                                              u16* __restrict__ attbf) {
  int t = threadIdx.x;
  int head = t & 15, dh = (t >> 4) & 1, lsub = t >> 5;
  int l = blockIdx.x * 8 + lsub;
  int b = blockIdx.z;
  size_t row = ((size_t)(b * 1024 + l)) * 1024 + head * 64 + dh * 32;
  size_t rbase = (size_t)b * 1024 + head * 64 + dh * 32;

  float qf[32];
  {
    const short8* qp = reinterpret_cast<const short8*>(q + row);
#pragma unroll
    for (int j = 0; j < 4; ++j) {
      short8 qv = qp[j];
#pragma unroll
      for (int e = 0; e < 8; ++e) qf[j * 8 + e] = bf2f((u16)qv[e]);
    }
  }
  float s[7];
#pragma unroll
  for (int u = 0; u < 5; ++u) {
    int lk = l + u - 2;
    float su = 0.f;
    if (lk >= 0 && lk < L_) {
      const short8* kp =
          reinterpret_cast<const short8*>(k + ((size_t)(b * 1024 + lk)) * 1024 + head * 64 + dh * 32);
#pragma unroll
      for (int j = 0; j < 4; ++j) {
        short8 kv = kp[j];
#pragma unroll
        for (int e = 0; e < 8; ++e) su = fmaf(qf[j * 8 + e], bf2f((u16)kv[e]), su);
      }
    }
    s[u] = su;
  }
  {
    float su = 0.f;
    const short8* kp = reinterpret_cast<const short8*>(ke + row);
#pragma unroll
    for (int j = 0; j < 4; ++j) {
      short8 kv = kp[j];
#pragma unroll
      for (int e = 0; e < 8; ++e) su = fmaf(qf[j * 8 + e], bf2f((u16)kv[e]), su);
    }
    s[5] = su;
  }
  {
    float su = 0.f;
    const float4* rp = reinterpret_cast<const float4*>(rk + rbase);
#pragma unroll
    for (int j = 0; j < 8; ++j) {
      float4 r4 = rp[j];
      su = fmaf(qf[j * 4 + 0], r4.x, su);
      su = fmaf(qf[j * 4 + 1], r4.y, su);
      su = fmaf(qf[j * 4 + 2], r4.z, su);
      su = fmaf(qf[j * 4 + 3], r4.w, su);
    }
    s[6] = su;
  }
#pragma unroll
  for (int u = 0; u < 7; ++u) s[u] += __shfl_xor(s[u], 16);
  float m = -1e30f;
#pragma unroll
  for (int u = 0; u < 7; ++u) {
    s[u] *= 0.125f;
    m = fmaxf(m, s[u]);
  }
  float e[7], tot = 0.f;
#pragma unroll
  for (int u = 0; u < 7; ++u) {
    e[u] = expf(s[u] - m);
    tot += e[u];
  }
  float inv = 1.f / tot;
#pragma unroll
  for (int u = 0; u < 7; ++u) e[u] *= inv;

  float av[32];
  {
    const float4* rp = reinterpret_cast<const float4*>(rv + rbase);
#pragma unroll
    for (int j = 0; j < 8; ++j) {
      float4 r4 = rp[j];
      av[j * 4 + 0] = e[6] * r4.x;
      av[j * 4 + 1] = e[6] * r4.y;
      av[j * 4 + 2] = e[6] * r4.z;
      av[j * 4 + 3] = e[6] * r4.w;
    }
  }
  {
    const short8* vp = reinterpret_cast<const short8*>(ve + row);
#pragma unroll
    for (int j = 0; j < 4; ++j) {
      short8 vv = vp[j];
#pragma unroll
      for (int ee = 0; ee < 8; ++ee) av[j * 8 + ee] = fmaf(e[5], bf2f((u16)vv[ee]), av[j * 8 + ee]);
    }
  }
#pragma unroll
  for (int u = 0; u < 5; ++u) {
    int lk = l + u - 2;
    if (lk >= 0 && lk < L_) {
      const short8* vp =
          reinterpret_cast<const short8*>(v + ((size_t)(b * 1024 + lk)) * 1024 + head * 64 + dh * 32);
#pragma unroll
      for (int j = 0; j < 4; ++j) {
        short8 vv = vp[j];
#pragma unroll
        for (int ee = 0; ee < 8; ++ee) av[j * 8 + ee] = fmaf(e[u], bf2f((u16)vv[ee]), av[j * 8 + ee]);
      }
    }
  }
  u16 ob[32];
#pragma unroll
  for (int j = 0; j < 32; ++j) ob[j] = f2bf(av[j]);
  uint4* d4 = reinterpret_cast<uint4*>(attbf + row);
  const uint4* s4 = reinterpret_cast<const uint4*>(ob);
#pragma unroll
  for (int j = 0; j < 4; ++j) d4[j] = s4[j];
}

// ---------- msa2 partial: block = (n, chunk, b); unnormalized sums ----------
// e_p = exp(score_p) (exact softmax equivalent); partial E = sum e, partial
// w[d] = sum e_p * k[d][p] over this chunk's p range. v = k (faithful).
__global__ __launch_bounds__(256) void k_msa2p(const float* __restrict__ rq,
                                               const float* __restrict__ kk,
                                               const int* __restrict__ mask,
                                               float* __restrict__ pw,
                                               float* __restrict__ pE) {
  int n = blockIdx.x, c = blockIdx.y, b = blockIdx.z;
  int tid = threadIdx.x;
  __shared__ float sq_[HD_];
  __shared__ float se[260];
  size_t rb = (size_t)(b * NH_ + n) * HD_;
  if (tid < HD_) sq_[tid] = rq[rb + tid];
  __syncthreads();
  const float* kb = kk + rb * (size_t)(L_ + 1);
  int p0 = c * 256;
  {
    int p = p0 + tid;
    float e;
    if (p > 0 && mask[b * L_ + p - 1] == 0) {
      e = 0.f;
    } else {
      float acc = 0.f;
      for (int d = 0; d < HD_; ++d) acc = fmaf(sq_[d], kb[(size_t)d * (L_ + 1) + p], acc);
      e = expf(acc * 0.125f);
    }
    se[tid] = e;
  }
  int nP = 256;
  if (c == 3) {
    nP = 257;
    if (tid == 0) {
      float e;
      if (mask[b * L_ + 1023] == 0) {
        e = 0.f;
      } else {
        float acc = 0.f;
        for (int d = 0; d < HD_; ++d) acc = fmaf(sq_[d], kb[(size_t)d * (L_ + 1) + 1024], acc);
        e = expf(acc * 0.125f);
      }
      se[256] = e;
    }
  }
  __syncthreads();
  int lane = tid & 63, w = tid >> 6;
  if (w == 0) {
    float E = 0.f;
    for (int i = lane; i < nP; i += 64) E += se[i];
#pragma unroll
    for (int off = 32; off; off >>= 1) E += __shfl_xor(E, off);
    if (lane == 0) pE[((size_t)(b * NH_ + n)) * 4 + c] = E;
  }
  for (int dd = 0; dd < 16; ++dd) {
    int d = w * 16 + dd;
    const float* kd = kb + (size_t)d * (L_ + 1) + p0;
    float a = 0.f;
    for (int i = lane; i < nP; i += 64) a = fmaf(se[i], kd[i], a);
#pragma unroll
    for (int off = 32; off; off >>= 1) a += __shfl_xor(a, off);
    if (lane == 0) pw[(((size_t)(b * NH_ + n)) * 4 + c) * HD_ + d] = a;
  }
}

// ---------- msa2 reduce: satt = (sum_c w) / (sum_c E) ----------
__global__ void k_msa2r(const float* __restrict__ pw, const float* __restrict__ pE,
                        float* __restrict__ satt) {
  int i = blockIdx.x * 256 + threadIdx.x;  // B*NH*HD
  int bn = i >> 6, d = i & 63;
  float E = pE[bn * 4 + 0] + pE[bn * 4 + 1] + pE[bn * 4 + 2] + pE[bn * 4 + 3];
  float ws = pw[((size_t)bn * 4 + 0) * HD_ + d] + pw[((size_t)bn * 4 + 1) * HD_ + d] +
             pw[((size_t)bn * 4 + 2) * HD_ + d] + pw[((size_t)bn * 4 + 3) * HD_ + d];
  satt[i] = ws / E;
}

// ---------- final: out = pad ? 0 : nodes (fused last-iter zeroing) ----------
__global__ void k_final(const float* __restrict__ nodes, const int* __restrict__ mask,
                        float* __restrict__ out) {
  int i = blockIdx.x * 256 + threadIdx.x;
  int row = i >> 8;
  int b = row >> 10, l = row & 1023;
  float4 v = (mask[b * L_ + l] == 0) ? float4{0.f, 0.f, 0.f, 0.f}
                                     : reinterpret_cast<const float4*>(nodes)[i];
  reinterpret_cast<float4*>(out)[i] = v;
}

__global__ void k_copy_relay(const float* __restrict__ relay, float* __restrict__ out) {
  int i = blockIdx.x * 256 + threadIdx.x;
  out[i] = relay[i];
}

}  // namespace

extern "C" void kernel_launch(void* const* d_in, const int* in_sizes, int n_in,
                              void* d_out, int out_size, void* d_ws, size_t ws_size,
                              hipStream_t stream) {
  (void)in_sizes; (void)n_in; (void)out_size; (void)ws_size;
  const float* data = (const float*)d_in[0];
  const int* mask = (const int*)d_in[1];
  const float* ln_s = (const float*)d_in[2];
  const float* ln_b = (const float*)d_in[3];
  const float* rwq = (const float*)d_in[4];
  const float* rwq_b = (const float*)d_in[5];
  const float* rwk = (const float*)d_in[6];
  const float* rwk_b = (const float*)d_in[7];
  const float* rwv = (const float*)d_in[8];
  const float* rwv_b = (const float*)d_in[9];
  const float* rwo = (const float*)d_in[10];
  const float* rwo_b = (const float*)d_in[11];
  const float* swq = (const float*)d_in[12];
  const float* swq_b = (const float*)d_in[13];
  const float* swk = (const float*)d_in[14];
  const float* swk_b = (const float*)d_in[15];
  const float* swo = (const float*)d_in[16];
  const float* swo_b = (const float*)d_in[17];
  float* out = (float*)d_out;

  const size_t SZ = (size_t)B_ * ND_ * L_;  // 4M elements
  float* f = (float*)d_ws;
  float* nodes = f; f += SZ;                       // fp32 [B,L,H]
  float* kkb = f; f += (size_t)B_ * ND_ * (L_ + 1);
  float* part = f; f += (size_t)B_ * 8 * H_;
  float* relay = f; f += B_ * H_;
  float* rk = f; f += B_ * ND_;
  float* rv = f; f += B_ * ND_;
  float* rq = f; f += B_ * ND_;
  float* satt = f; f += B_ * ND_;
  float* pw = f; f += (size_t)B_ * NH_ * 4 * HD_;
  float* pE = f; f += B_ * NH_ * 4;
  u16* u = (u16*)f;
  u16* xn_bf = u; u += SZ;       // [B,L,H]
  u16* embs_bf = u; u += SZ;     // [B,L,H]
  u16* att_bf = u; u += SZ;      // [B,L,ND]
  u16* nodes_bf = u; u += SZ;    // [B,L,H]
  u16* qkv5_bf = u; u += 5 * SZ; // [5][B,L,ND]: q,k,v,ke,ve
  u16* wq_bf = u; u += SZ;
  u16* wk_bf = u; u += SZ;
  u16* wv_bf = u; u += SZ;
  u16* wo_bf = u; u += SZ;
  u16* swk_bf = u; u += SZ;

  k_prep<<<dim3(4096, 7), 256, 0, stream>>>(data, rwq, rwk, rwv, rwo, swk,
                                            embs_bf, wq_bf, wk_bf, wv_bf, wo_bf, swk_bf, nodes);
  k_relay_part<<<dim3(H_ / 256, 8, B_), 256, 0, stream>>>(data, part);
  k_relay_reduce<<<dim3((B_ * H_) / 256), 256, 0, stream>>>(part, relay);

  for (int i = 0; i < ITERS_; ++i) {
    const u16* wq_i = wq_bf + (size_t)i * ND_ * H_;
    const u16* wk_i = wk_bf + (size_t)i * ND_ * H_;
    const u16* wv_i = wv_bf + (size_t)i * ND_ * H_;
    const u16* wo_i = wo_bf + (size_t)i * H_ * ND_;
    const u16* sk_i = swk_bf + (size_t)i * ND_ * H_;

    k_layernorm_bf<<<dim3(B_ * L_ / 4), 256, 0, stream>>>(nodes, ln_s + i * H_, ln_b + i * H_,
                                                          mask, xn_bf, i > 0 ? 1 : 0);
    // q,k,v,ke,ve in one dispatch
    k_gemm5<<<dim3(32, 40), 256, 0, stream>>>(wq_i, wk_i, wv_i,
                                              rwq_b + i * ND_, rwk_b + i * ND_, rwv_b + i * ND_,
                                              xn_bf, embs_bf, qkv5_bf);
    // rk, rv (fp32 weights)
    k_matvec2<<<dim3(256, B_, 2), 256, 0, stream>>>(
        rwk + (size_t)i * ND_ * H_, rwk_b + i * ND_, rk, ND_, 1,
        rwv + (size_t)i * ND_ * H_, rwv_b + i * ND_, rv, ND_, 1, relay);
    k_msa1<<<dim3(L_ / 8, 1, B_), 256, 0, stream>>>(qkv5_bf, qkv5_bf + SZ, qkv5_bf + 2 * SZ,
                                                    qkv5_bf + 3 * SZ, qkv5_bf + 4 * SZ, rk, rv, att_bf);
    k_gemm_wo<<<dim3(32, 8), 256, 0, stream>>>(wo_i, rwo_b + i * H_, att_bf, nodes, nodes_bf);
    // rq and kkb col0 (old relay)
    k_matvec2<<<dim3(256, B_, 2), 256, 0, stream>>>(
        swq + (size_t)i * ND_ * H_, swq_b + i * ND_, rq, ND_, 1,
        swk + (size_t)i * ND_ * H_, swk_b + i * ND_, kkb, (long)ND_ * (L_ + 1), L_ + 1, relay);
    k_gemm_kkb<<<dim3(32, 8), 256, 0, stream>>>(sk_i, swk_b + i * ND_, nodes_bf, kkb);
    k_msa2p<<<dim3(NH_, 4, B_), 256, 0, stream>>>(rq, kkb, mask, pw, pE);
    k_msa2r<<<dim3((B_ * NH_ * HD_) / 256), 256, 0, stream>>>(pw, pE, satt);
    k_matvec<<<dim3(256, B_), 256, 0, stream>>>(swo + (size_t)i * H_ * ND_, swo_b + i * H_, satt, relay);
  }
  k_final<<<4096, 256, 0, stream>>>(nodes, mask, out);
  k_copy_relay<<<dim3((B_ * H_) / 256), 256, 0, stream>>>(relay, out + (size_t)B_ * L_ * H_);
}